// Round 18
// baseline (493.250 us; speedup 1.0000x reference)
//
#include <hip/hip_runtime.h>
#include <hip/hip_bf16.h>
#include <math.h>

#define BB 256
#define TT 128
#define DD 1024
#define CFF 128
#define HH 128
#define G4 512
#define NK 9

typedef __attribute__((ext_vector_type(8))) short bf16x8;
typedef __attribute__((ext_vector_type(4))) float f32x4;

__device__ __forceinline__ float bf_lo(unsigned u){ union{unsigned u; float f;} v; v.u = u << 16; return v.f; }
__device__ __forceinline__ float bf_hi(unsigned u){ union{unsigned u; float f;} v; v.u = u & 0xffff0000u; return v.f; }
__device__ __forceinline__ unsigned f2bf(float x){
    union{float f; unsigned u;} v; v.f = x;
    unsigned r = v.u + 0x7fffu + ((v.u >> 16) & 1u);
    return r >> 16;
}
__device__ __forceinline__ float fsig_fast(float x){
    return __builtin_amdgcn_rcpf(1.0f + __builtin_amdgcn_exp2f(-1.44269504f * x));
}
__device__ __forceinline__ float ftanh_fast(float x){
    return 1.0f - 2.0f * __builtin_amdgcn_rcpf(1.0f + __builtin_amdgcn_exp2f(2.88539008f * x));
}
__device__ __forceinline__ float gelu_exact(float x){
    return 0.5f*x*(1.0f + erff(x*0.70710678118654752440f));
}

// ---------------- unified weight prep (single launch) ----------------
__global__ __launch_bounds__(256) void prep_all_kernel(
    const float* __restrict__ c5w, const float* __restrict__ c7w, const float* __restrict__ c9w,
    const float* __restrict__ Wihf, const float* __restrict__ Wihb,
    const float* __restrict__ bihf, const float* __restrict__ bhhf,
    const float* __restrict__ bihb, const float* __restrict__ bhhb,
    const float* __restrict__ c7b, const float* __restrict__ c9b,
    ushort* __restrict__ Wk5, ushort* __restrict__ Wk79, ushort* __restrict__ Wxg,
    float* __restrict__ bias_xg, float* __restrict__ cb79)
{
    int i = blockIdx.x*256 + threadIdx.x;
    if (i < 655360) {
        int k = i % 5, d = (i / 5) & 1023, f = i / 5120;
        Wk5[((size_t)(k*128 + f))*1024 + d] = (ushort)f2bf(c5w[((size_t)f*1024 + d)*5 + k]);
    } else if (i < 950272) {
        int j = i - 655360;
        int k = j % 9, d = (j / 9) & 255, f = j / 2304;
        int ks = k - 1;
        float v = (ks >= 0 && ks < 7) ? c7w[((size_t)f*256 + d)*7 + ks] : 0.f;
        Wk79[((size_t)(k*128 + f))*256 + d] = (ushort)f2bf(v);
    } else if (i < 1245184) {
        int j = i - 950272;
        int k = j % 9, d = (j / 9) & 255, f = j / 2304;
        Wk79[294912 + ((size_t)(k*128 + f))*256 + d] = (ushort)f2bf(c9w[((size_t)f*256 + d)*9 + k]);
    } else if (i < 1310720) {
        int j = i - 1245184;
        Wxg[j] = (ushort)f2bf(Wihf[j]);
    } else if (i < 1376256) {
        int j = i - 1310720;
        Wxg[65536 + j] = (ushort)f2bf(Wihb[j]);
    } else if (i < 1376768) {
        int j = i - 1376256;
        bias_xg[j] = bihf[j] + bhhf[j];
    } else if (i < 1377280) {
        int j = i - 1376768;
        bias_xg[512 + j] = bihb[j] + bhhb[j];
    } else if (i < 1377536) {
        int j = i - 1377280;
        cb79[j] = (j < 128) ? c7b[j] : c9b[j - 128];
    }
}

// ---------------- implicit-GEMM conv via MFMA v5 ----------------
// XGT layout: [dir][t][b][quad][g][e]  (idx = b*512 + (f>>2)*16 + g*4 + (f&3))
// XGT computes the TRANSPOSED gemm (swap MFMA operands) so each thread owns
// 4 consecutive quad-aligned f for one t -> epilogue = 8B ushort4 stores.
template<int CIN, int KS, int KSE_MAX, int SPLIT, bool IN_F32, bool OUT_BF16,
         bool XGT = false, bool CO_BY = false>
__global__ __launch_bounds__(256, 1) void conv_mfma_kernel(
    const void* __restrict__ in_v,
    const ushort* __restrict__ Wk_g,
    const float* __restrict__ bias_g,
    void* __restrict__ outA_v, void* __restrict__ outB_v,
    int OS, int co)
{
    constexpr int PAD = KS / 2;
    constexpr int ROWS = 128 + 2 * PAD;
    constexpr int NSTEP = (SPLIT == 1) ? (CIN / 64) : (CIN / 32);
    constexpr int ATOT = IN_F32 ? ROWS * 8 : ROWS * 4;
    constexpr int BTOT = KSE_MAX * 128 * 4;
    constexpr int AIT = (ATOT + 255) / 256;
    constexpr int BIT = (BTOT + 255) / 256;

    __shared__ ushort A_lds[ROWS * 32];
    __shared__ ushort B_lds[KSE_MAX * 128 * 32];

    const int tid = threadIdx.x;
    const int b   = blockIdx.x;
    const int by  = blockIdx.y;
    const int z   = blockIdx.z;
    const int dbase = (SPLIT == 1) ? z * (CIN / 2) : 0;
    const int k0    = (SPLIT == 2) ? z * KSE_MAX : 0;
    const int kse   = (SPLIT == 2) ? ((z == 0) ? KSE_MAX : (KS - KSE_MAX)) : KS;
    const ushort* __restrict__ Wk = Wk_g + (size_t)by * (size_t)(128 * CIN * KS);
    const float* __restrict__ bias = bias_g + by * 128;
    const int co_eff = co + (CO_BY ? (by << 7) : 0);

    float4 aRf[AIT];
    int4   aRb[AIT];
    int4   bR[BIT];

    auto stage_load = [&](int s) {
        const int d0 = dbase + s * 32;
        if constexpr (IN_F32) {
            const float* __restrict__ inp = (const float*)in_v;
#pragma unroll
            for (int it = 0; it < AIT; ++it) {
                int i = tid + it * 256;
                float4 v = make_float4(0.f, 0.f, 0.f, 0.f);
                if (i < ATOT) {
                    int r = i >> 3, c = i & 7;
                    int t = r - PAD;
                    if (t >= 0 && t < TT)
                        v = *reinterpret_cast<const float4*>(&inp[((size_t)b * TT + t) * CIN + d0 + c * 4]);
                }
                aRf[it] = v;
            }
        } else {
            const ushort* __restrict__ inp = (const ushort*)in_v;
#pragma unroll
            for (int it = 0; it < AIT; ++it) {
                int i = tid + it * 256;
                int4 v = make_int4(0, 0, 0, 0);
                if (i < ATOT) {
                    int r = i >> 2, c = i & 3;
                    int t = r - PAD;
                    if (t >= 0 && t < TT)
                        v = *reinterpret_cast<const int4*>(&inp[((size_t)b * TT + t) * CIN + d0 + c * 8]);
                }
                aRb[it] = v;
            }
        }
#pragma unroll
        for (int it = 0; it < BIT; ++it) {
            int i = tid + it * 256;
            int kk = i >> 9;
            int rem = i & 511;
            int f = rem >> 2, c = rem & 3;
            int4 v = make_int4(0, 0, 0, 0);
            if (kk < kse)
                v = *reinterpret_cast<const int4*>(&Wk[((size_t)((k0 + kk) * 128 + f)) * CIN + d0 + c * 8]);
            bR[it] = v;
        }
    };

    auto stage_write = [&]() {
        if constexpr (IN_F32) {
#pragma unroll
            for (int it = 0; it < AIT; ++it) {
                int i = tid + it * 256;
                if (i < ATOT) {
                    int r = i >> 3, c = i & 7;
                    float4 v = aRf[it];
                    ushort4 h;
                    h.x = (ushort)f2bf(v.x); h.y = (ushort)f2bf(v.y);
                    h.z = (ushort)f2bf(v.z); h.w = (ushort)f2bf(v.w);
                    int slot = (c >> 1) ^ (r & 3);
                    *reinterpret_cast<ushort4*>(&A_lds[r * 32 + slot * 8 + (c & 1) * 4]) = h;
                }
            }
        } else {
#pragma unroll
            for (int it = 0; it < AIT; ++it) {
                int i = tid + it * 256;
                if (i < ATOT) {
                    int r = i >> 2, c = i & 3;
                    int slot = c ^ (r & 3);
                    *reinterpret_cast<int4*>(&A_lds[r * 32 + slot * 8]) = aRb[it];
                }
            }
        }
#pragma unroll
        for (int it = 0; it < BIT; ++it) {
            int i = tid + it * 256;
            int kk = i >> 9;
            int rem = i & 511;
            int f = rem >> 2, c = rem & 3;
            int slot = c ^ (f & 3);
            *reinterpret_cast<int4*>(&B_lds[(kk * 128 + f) * 32 + slot * 8]) = bR[it];
        }
    };

    const int lane = tid & 63;
    const int wave = tid >> 6;
    const int lr = lane & 15;
    const int lk = lane >> 4;
    const int wm = wave >> 1;
    const int wn = wave & 1;

    f32x4 acc[4][4];
#pragma unroll
    for (int m = 0; m < 4; ++m)
#pragma unroll
        for (int n = 0; n < 4; ++n)
            acc[m][n] = (f32x4){0.f, 0.f, 0.f, 0.f};

    stage_load(0);
    stage_write();
    asm volatile("s_waitcnt lgkmcnt(0)" ::: "memory");
    __builtin_amdgcn_s_barrier();
    __builtin_amdgcn_sched_barrier(0);

    for (int s = 0; s < NSTEP; ++s) {
        if (s + 1 < NSTEP) stage_load(s + 1);
#pragma unroll
        for (int kk = 0; kk < KSE_MAX; ++kk) {
            bf16x8 af[4], bfr[4];
#pragma unroll
            for (int m = 0; m < 4; ++m) {
                int R = wm * 64 + m * 16 + lr + k0 + kk;
                if (kk >= kse) R = 0;
                af[m] = *reinterpret_cast<const bf16x8*>(&A_lds[R * 32 + ((lk ^ (R & 3)) * 8)]);
            }
#pragma unroll
            for (int n = 0; n < 4; ++n) {
                int Rb = kk * 128 + wn * 64 + n * 16 + lr;
                bfr[n] = *reinterpret_cast<const bf16x8*>(&B_lds[Rb * 32 + ((lk ^ (lr & 3)) * 8)]);
            }
#pragma unroll
            for (int m = 0; m < 4; ++m)
#pragma unroll
                for (int n = 0; n < 4; ++n) {
                    if constexpr (XGT)
                        acc[m][n] = __builtin_amdgcn_mfma_f32_16x16x32_bf16(bfr[n], af[m], acc[m][n], 0, 0, 0);
                    else
                        acc[m][n] = __builtin_amdgcn_mfma_f32_16x16x32_bf16(af[m], bfr[n], acc[m][n], 0, 0, 0);
                }
        }
        if (s + 1 < NSTEP) {
            asm volatile("s_waitcnt lgkmcnt(0)" ::: "memory");
            __builtin_amdgcn_s_barrier();
            __builtin_amdgcn_sched_barrier(0);
            stage_write();
            asm volatile("s_waitcnt lgkmcnt(0)" ::: "memory");
            __builtin_amdgcn_s_barrier();
            __builtin_amdgcn_sched_barrier(0);
        }
    }

    if constexpr (XGT) {
        // D^T: row(lk*4+q) = f, col(lr) = t. Thread owns quad-aligned f0..f0+3 at one t.
        const int dirg = by >> 2;
        const int g = by & 3;
        ushort* __restrict__ outp = (ushort*)outA_v;
#pragma unroll
        for (int n = 0; n < 4; ++n) {
            const int f0 = wn * 64 + n * 16 + (lk << 2);
            float b4[4];
#pragma unroll
            for (int q = 0; q < 4; ++q) b4[q] = bias[f0 + q];
#pragma unroll
            for (int m = 0; m < 4; ++m) {
                const int t = wm * 64 + m * 16 + lr;
                ushort4 hh;
                hh.x = (ushort)f2bf(acc[m][n][0] + b4[0]);
                hh.y = (ushort)f2bf(acc[m][n][1] + b4[1]);
                hh.z = (ushort)f2bf(acc[m][n][2] + b4[2]);
                hh.w = (ushort)f2bf(acc[m][n][3] + b4[3]);
                size_t idx = (size_t)dirg * 16777216u + (size_t)t * 131072u
                           + (size_t)b * 512u + (size_t)(((f0 >> 2) << 4) + (g << 2));
                *reinterpret_cast<ushort4*>(&outp[idx]) = hh;
            }
        }
    } else {
        const bool addb = (SPLIT == 0) || (z == 0);
        void* out_v = (SPLIT != 0 && z == 1) ? outB_v : outA_v;
        float bv[4];
#pragma unroll
        for (int n = 0; n < 4; ++n) bv[n] = addb ? bias[wn * 64 + n * 16 + lr] : 0.f;
#pragma unroll
        for (int m = 0; m < 4; ++m) {
#pragma unroll
            for (int n = 0; n < 4; ++n) {
                int f = wn * 64 + n * 16 + lr;
#pragma unroll
                for (int q = 0; q < 4; ++q) {
                    int trow = wm * 64 + m * 16 + lk * 4 + q;
                    float val = acc[m][n][q] + bv[n];
                    size_t idx = ((size_t)b * TT + trow) * (size_t)OS + co_eff + f;
                    if constexpr (OUT_BF16)
                        ((ushort*)out_v)[idx] = (ushort)f2bf(val);
                    else
                        ((float*)out_v)[idx] = val;
                }
            }
        }
    }
}

// ---------------- BN stats (sums partials y + y2) ----------------
__global__ __launch_bounds__(256) void bn_stats_kernel(
    const float* __restrict__ y, const float* __restrict__ y2, int C, int rows_per_blk,
    float* __restrict__ sum, float* __restrict__ sqsum)
{
    int tpc = 256 / C;
    int c = threadIdx.x & (C - 1);
    int sub = threadIdx.x / C;
    size_t r0 = (size_t)blockIdx.x * rows_per_blk;
    float s = 0.f, s2 = 0.f;
    for (int r = sub; r < rows_per_blk; r += tpc) {
        size_t i = (r0 + r)*C + c;
        float v = y[i] + y2[i];
        s += v; s2 += v*v;
    }
    __shared__ float ls[256], ls2[256];
    ls[threadIdx.x] = s; ls2[threadIdx.x] = s2;
    __syncthreads();
    if (sub == 0) {
        for (int k = 1; k < tpc; ++k) { s += ls[c + k*C]; s2 += ls2[c + k*C]; }
        atomicAdd(&sum[c], s);
        atomicAdd(&sqsum[c], s2);
    }
}

// ---------------- BN1 + GELU, bf16 output ----------------
__global__ __launch_bounds__(256) void bn_gelu_bf16_kernel(
    const float* __restrict__ y, const float* __restrict__ y2,
    const float* __restrict__ sum, const float* __restrict__ sqsum,
    const float* __restrict__ g, const float* __restrict__ beta,
    ushort* __restrict__ out, float inv_n)
{
    size_t i = (size_t)blockIdx.x*256 + threadIdx.x;
    int c = (int)(i & 127);
    float m = sum[c] * inv_n;
    float var = fmaxf(sqsum[c]*inv_n - m*m, 0.f);
    float xv = (y[i] + y2[i] - m) * rsqrtf(var + 1e-5f) * g[c] + beta[c];
    out[i] = (ushort)f2bf(gelu_exact(xv));
}

// ---------------- MFMA bi-LSTM v5b: contiguous 32B xg records (2 x dwordx4) ----------------
__global__ __launch_bounds__(512, 1) void lstm_mfma_kernel(
    const ushort* __restrict__ xg2,
    const float* __restrict__ Whhf, const float* __restrict__ Whhb,
    ushort* __restrict__ hfb)
{
    const int tid = threadIdx.x;
    const int lane = tid & 63;
    const int w = tid >> 6;
    const int jc = lane & 15;
    const int kq = lane >> 4;
    const int dir = blockIdx.x >> 4;
    const int b0 = (blockIdx.x & 15) << 4;
    const float* __restrict__ Whh = dir ? Whhb : Whhf;

    bf16x8 Wf[4][4];
#pragma unroll
    for (int g = 0; g < 4; ++g) {
        const float* wr = &Whh[(size_t)((g << 7) + (w << 4) + jc) * HH + (kq << 3)];
#pragma unroll
        for (int s = 0; s < 4; ++s) {
            float4 v0 = *reinterpret_cast<const float4*>(wr + (s << 5));
            float4 v1 = *reinterpret_cast<const float4*>(wr + (s << 5) + 4);
            union { bf16x8 v; ushort u[8]; } pk;
            pk.u[0] = (ushort)f2bf(v0.x); pk.u[1] = (ushort)f2bf(v0.y);
            pk.u[2] = (ushort)f2bf(v0.z); pk.u[3] = (ushort)f2bf(v0.w);
            pk.u[4] = (ushort)f2bf(v1.x); pk.u[5] = (ushort)f2bf(v1.y);
            pk.u[6] = (ushort)f2bf(v1.z); pk.u[7] = (ushort)f2bf(v1.w);
            Wf[g][s] = pk.v;
        }
    }

    __shared__ ushort h_lds[2][16 * 136];
    for (int i = tid; i < 16 * 136; i += 512) h_lds[0][i] = 0;
    f32x4 creg = (f32x4){0.f, 0.f, 0.f, 0.f};

    const ushort* __restrict__ xb = xg2 + (size_t)dir * 16777216u
        + (size_t)(b0 + jc) * 512u + (size_t)((w * 4 + kq) << 4);

    uint4 xA0, xA1, xB0, xB1;
    {
        int tt0 = dir ? (TT - 1) : 0;
        int tt1 = dir ? (TT - 2) : 1;
        const uint4* pA = reinterpret_cast<const uint4*>(xb + (size_t)tt0 * 131072u);
        const uint4* pB = reinterpret_cast<const uint4*>(xb + (size_t)tt1 * 131072u);
        xA0 = pA[0]; xA1 = pA[1];
        xB0 = pB[0]; xB1 = pB[1];
    }

    __syncthreads();

    int cur = 0;
    const int hrd = jc * 136 + (kq << 3);
    const int col0 = (w << 4) + (kq << 2);

    auto step = [&](int t, uint4& x0, uint4& x1) {
        const int tt_c = dir ? (TT - 1 - t) : t;
        f32x4 acc[4];
        {
            unsigned xu[8] = {x0.x, x0.y, x0.z, x0.w, x1.x, x1.y, x1.z, x1.w};
#pragma unroll
            for (int g = 0; g < 4; ++g) {
                acc[g][0] = bf_lo(xu[2*g]);
                acc[g][1] = bf_hi(xu[2*g]);
                acc[g][2] = bf_lo(xu[2*g + 1]);
                acc[g][3] = bf_hi(xu[2*g + 1]);
            }
        }
        {
            int t2 = t + 2; if (t2 >= TT) t2 = TT - 1;
            int ttn = dir ? (TT - 1 - t2) : t2;
            const uint4* p = reinterpret_cast<const uint4*>(xb + (size_t)ttn * 131072u);
            x0 = p[0]; x1 = p[1];
        }
        bf16x8 Hf[4];
#pragma unroll
        for (int s = 0; s < 4; ++s)
            Hf[s] = *reinterpret_cast<const bf16x8*>(&h_lds[cur][hrd + (s << 5)]);
#pragma unroll
        for (int s = 0; s < 4; ++s)
#pragma unroll
            for (int g = 0; g < 4; ++g)
                acc[g] = __builtin_amdgcn_mfma_f32_16x16x32_bf16(Wf[g][s], Hf[s], acc[g], 0, 0, 0);
        float hv[4];
#pragma unroll
        for (int r = 0; r < 4; ++r) {
            float iv = fsig_fast(acc[0][r]);
            float fv = fsig_fast(acc[1][r]);
            float gv = ftanh_fast(acc[2][r]);
            float ov = fsig_fast(acc[3][r]);
            float c = fv * creg[r] + iv * gv;
            creg[r] = c;
            hv[r] = ov * ftanh_fast(c);
        }
        ushort4 hb;
        hb.x = (ushort)f2bf(hv[0]); hb.y = (ushort)f2bf(hv[1]);
        hb.z = (ushort)f2bf(hv[2]); hb.w = (ushort)f2bf(hv[3]);
        const int nxt = cur ^ 1;
        *reinterpret_cast<ushort4*>(&h_lds[nxt][jc * 136 + col0]) = hb;
        *reinterpret_cast<ushort4*>(&hfb[((size_t)(b0 + jc) * TT + tt_c) * 256 + (dir << 7) + col0]) = hb;
        asm volatile("s_waitcnt lgkmcnt(0)" ::: "memory");
        __builtin_amdgcn_s_barrier();
        __builtin_amdgcn_sched_barrier(0);
        cur = nxt;
    };

    for (int t = 0; t < TT; t += 2) {
        step(t, xA0, xA1);
        step(t + 1, xB0, xB1);
    }
}

// ---------------- fused BN2 + GELU + logits (256 blocks x 128 thr) ----------------
__global__ __launch_bounds__(128) void logits_bn_kernel(
    const float* __restrict__ a, const float* __restrict__ bpart,
    const float* __restrict__ sum, const float* __restrict__ sqsum,
    const float* __restrict__ g, const float* __restrict__ beta,
    const float* __restrict__ cw, const float* __restrict__ cb,
    float* __restrict__ lg, float inv_n)
{
    __shared__ float wls[NK*256];
    __shared__ float sc_lds[256], sh_lds[256];
    for (int i = threadIdx.x; i < NK*256; i += 128) wls[i] = cw[i];
    for (int c = threadIdx.x; c < 256; c += 128) {
        float m = sum[c] * inv_n;
        float var = fmaxf(sqsum[c]*inv_n - m*m, 0.f);
        float rs = rsqrtf(var + 1e-5f);
        float s = rs * g[c];
        sc_lds[c] = s;
        sh_lds[c] = beta[c] - m * s;
    }
    __syncthreads();
    size_t row = (size_t)blockIdx.x*128 + threadIdx.x;
    const float* ar = &a[row*256];
    const float* br = &bpart[row*256];
    float acc[NK];
#pragma unroll
    for (int k = 0; k < NK; ++k) acc[k] = 0.f;
    for (int c = 0; c < 256; c += 4) {
        float4 av = *reinterpret_cast<const float4*>(&ar[c]);
        float4 bv = *reinterpret_cast<const float4*>(&br[c]);
        float vv[4] = {av.x + bv.x, av.y + bv.y, av.z + bv.z, av.w + bv.w};
#pragma unroll
        for (int j = 0; j < 4; ++j) {
            float xv = vv[j] * sc_lds[c + j] + sh_lds[c + j];
            float f = gelu_exact(xv);
#pragma unroll
            for (int k = 0; k < NK; ++k)
                acc[k] += f * wls[k*256 + c + j];
        }
    }
#pragma unroll
    for (int k = 0; k < NK; ++k) lg[row*NK + k] = acc[k] + cb[k];
}

// ---------------- weighted CE ----------------
__global__ __launch_bounds__(256) void ce_kernel(
    const float* __restrict__ lg, const int* __restrict__ labels,
    const float* __restrict__ cw, float* __restrict__ acc2)
{
    size_t i = (size_t)blockIdx.x*256 + threadIdx.x;
    const float* l = &lg[i*NK];
    float mx = -1e30f;
#pragma unroll
    for (int k = 0; k < NK; ++k) mx = fmaxf(mx, l[k]);
    float se = 0.f;
#pragma unroll
    for (int k = 0; k < NK; ++k) se += expf(l[k] - mx);
    float lz = mx + logf(se);
    int y = labels[i];
    bool valid = (y != -100);
    int yi = valid ? y : 0;
    float nll = lz - l[yi];
    float wv = valid ? cw[yi] : 0.f;
    __shared__ float s1[256], s2[256];
    s1[threadIdx.x] = wv*nll;
    s2[threadIdx.x] = wv;
    __syncthreads();
    for (int s = 128; s > 0; s >>= 1) {
        if (threadIdx.x < s) { s1[threadIdx.x] += s1[threadIdx.x + s]; s2[threadIdx.x] += s2[threadIdx.x + s]; }
        __syncthreads();
    }
    if (threadIdx.x == 0) { atomicAdd(&acc2[0], s1[0]); atomicAdd(&acc2[1], s2[0]); }
}

// ---------------- CRF ----------------
__global__ __launch_bounds__(64) void crf_kernel(
    const float* __restrict__ lg, const int* __restrict__ att,
    const int* __restrict__ labels, const float* __restrict__ startv,
    const float* __restrict__ trans, const float* __restrict__ endv,
    float* __restrict__ numo, float* __restrict__ logzo)
{
    int b = blockIdx.x;
    int lane = threadIdx.x;
    int lane_c = (lane < NK) ? lane : 0;
    const float* em = &lg[(size_t)b*TT*NK];
    float tr[NK];
#pragma unroll
    for (int i = 0; i < NK; ++i) tr[i] = trans[i*NK + lane_c];
    float score = startv[lane_c] + em[lane_c];

    for (int t = 1; t < TT; ++t) {
        int lt = labels[b*TT + t];
        bool m = (att[b*TT + t] != 0) && (lt != -100);
        float vals[NK];
#pragma unroll
        for (int i = 0; i < NK; ++i)
            vals[i] = __shfl(score, i, 64) + tr[i];
        if (m) {
            float mx = vals[0];
#pragma unroll
            for (int i = 1; i < NK; ++i) mx = fmaxf(mx, vals[i]);
            float sm = 0.f;
#pragma unroll
            for (int i = 0; i < NK; ++i) sm += expf(vals[i] - mx);
            score = mx + logf(sm) + em[t*NK + lane_c];
        }
    }
    float fin = (lane < NK) ? (score + endv[lane_c]) : -1e30f;
    float mx = -1e30f;
#pragma unroll
    for (int i = 0; i < NK; ++i) mx = fmaxf(mx, __shfl(fin, i, 64));
    float sm = 0.f;
#pragma unroll
    for (int i = 0; i < NK; ++i) sm += expf(__shfl(fin, i, 64) - mx);
    if (lane == 0) logzo[b] = mx + logf(sm);

    if (lane == 0) {
        int l0 = labels[b*TT];
        int tag0 = (l0 == -100) ? 0 : l0;
        bool m0 = (att[b*TT] != 0) && (l0 != -100);
        float num = startv[tag0] + em[tag0];
        int prev = tag0;
        int cnt = m0 ? 1 : 0;
        for (int t = 1; t < TT; ++t) {
            int lt = labels[b*TT + t];
            bool m = (att[b*TT + t] != 0) && (lt != -100);
            int tag = (lt == -100) ? 0 : lt;
            if (m) { num += trans[prev*NK + tag] + em[t*NK + tag]; cnt++; }
            prev = tag;
        }
        int le = cnt - 1; if (le < 0) le = 0; if (le >= TT) le = TT - 1;
        int ll = labels[b*TT + le];
        int ltag = (ll == -100) ? 0 : ll;
        num += endv[ltag];
        numo[b] = num;
    }
}

__global__ __launch_bounds__(256) void finalize_kernel(
    const float* __restrict__ numo, const float* __restrict__ logzo,
    const float* __restrict__ acc2, float* __restrict__ out)
{
    __shared__ float red[256];
    int tid = threadIdx.x;
    red[tid] = numo[tid] - logzo[tid];
    __syncthreads();
    for (int s = 128; s > 0; s >>= 1) {
        if (tid < s) red[tid] += red[tid + s];
        __syncthreads();
    }
    if (tid == 0) {
        float crf = -(red[0] / (float)BB);
        float ce = acc2[0] / acc2[1];
        out[0] = 0.8f*crf + 0.2f*ce;
    }
}

extern "C" void kernel_launch(void* const* d_in, const int* in_sizes, int n_in,
                              void* d_out, int out_size, void* d_ws, size_t ws_size,
                              hipStream_t stream)
{
    const float* emb   = (const float*)d_in[0];
    const int*   att   = (const int*)  d_in[1];
    const int*   lab   = (const int*)  d_in[2];
    const float* c5w   = (const float*)d_in[3];
    const float* c5b   = (const float*)d_in[4];
    const float* bn1g  = (const float*)d_in[5];
    const float* bn1b  = (const float*)d_in[6];
    const float* Wihf  = (const float*)d_in[7];
    const float* Whhf  = (const float*)d_in[8];
    const float* bihf  = (const float*)d_in[9];
    const float* bhhf  = (const float*)d_in[10];
    const float* Wihb  = (const float*)d_in[11];
    const float* Whhb  = (const float*)d_in[12];
    const float* bihb  = (const float*)d_in[13];
    const float* bhhb  = (const float*)d_in[14];
    const float* c7w   = (const float*)d_in[15];
    const float* c7b   = (const float*)d_in[16];
    const float* c9w   = (const float*)d_in[17];
    const float* c9b   = (const float*)d_in[18];
    const float* bn2g  = (const float*)d_in[19];
    const float* bn2b  = (const float*)d_in[20];
    const float* clsw  = (const float*)d_in[21];
    const float* clsb  = (const float*)d_in[22];
    const float* cstart= (const float*)d_in[23];
    const float* ctrans= (const float*)d_in[24];
    const float* cend  = (const float*)d_in[25];
    const float* cwts  = (const float*)d_in[26];
    (void)in_sizes; (void)n_in; (void)out_size; (void)ws_size;

    char* wsb = (char*)d_ws;
    size_t off = 0;
    auto alloc = [&](size_t bytes) { void* p = wsb + off; off += (bytes + 255) & ~(size_t)255; return p; };
    float*  y1      = (float*) alloc((size_t)4194304*4);   // (B*T,128) f32
    ushort* xg      = (ushort*)alloc((size_t)2*16777216*2);// [dir][t][b][quad][g][e] bf16 (64MB)
    ushort* hfb     = (ushort*)alloc((size_t)8388608*2);   // (B*T,256) bf16
    ushort* y1h     = (ushort*)alloc((size_t)4194304*2);   // (B*T,128) bf16 (post-BN1-GELU)
    float*  lg      = (float*) alloc((size_t)294912*4);
    ushort* Wk5     = (ushort*)alloc((size_t)655360*2);
    ushort* Wk79    = (ushort*)alloc((size_t)589824*2);    // [conv7 padded to 9 taps | conv9]
    ushort* Wxg     = (ushort*)alloc((size_t)131072*2);
    float*  bias_xg = (float*) alloc((size_t)1024*4);
    float*  cb79    = (float*) alloc((size_t)256*4);
    float*  stats   = (float*) alloc((size_t)2048*4);
    // aliases into the (temporally dead) xg region:
    float* y1b  = (float*)xg;                        // conv5 z=1 partial (16MB), dead before xg conv
    float* c79a = (float*)xg;                        // conv7/9 z=0 partials (32MB), after lstm
    float* c79b = (float*)(xg + 16777216);           // conv7/9 z=1 partials (32MB)
    float* bn1s = stats;
    float* bn1q = stats + 128;
    float* bn2s = stats + 256;
    float* bn2q = stats + 512;
    float* acc2 = stats + 768;
    float* numo = stats + 770;
    float* logzo = numo + 256;

    hipMemsetAsync(stats, 0, 770*sizeof(float), stream);

    prep_all_kernel<<<5381, 256, 0, stream>>>(c5w, c7w, c9w, Wihf, Wihb,
        bihf, bhhf, bihb, bhhb, c7b, c9b, Wk5, Wk79, Wxg, bias_xg, cb79);

    // conv5: K-channel split (z=0: d<512, z=1: d>=512) -> y1 / y1b
    conv_mfma_kernel<1024,5,5,1,true,false><<<dim3(256,1,2), 256, 0, stream>>>(emb, Wk5, c5b, y1, y1b, 128, 0);
    bn_stats_kernel<<<256, 256, 0, stream>>>(y1, y1b, 128, 128, bn1s, bn1q);
    bn_gelu_bf16_kernel<<<16384, 256, 0, stream>>>(y1, y1b, bn1s, bn1q, bn1g, bn1b, y1h, 1.0f/32768.f);

    conv_mfma_kernel<128,1,1,0,false,true,true><<<dim3(256,8,1), 256, 0, stream>>>(y1h, Wxg, bias_xg, xg, nullptr, 512, 0);
    lstm_mfma_kernel<<<32, 512, 0, stream>>>(xg, Whhf, Whhb, hfb);

    // merged conv7+conv9 (conv7 tap-padded to 9): by = weight set + col offset, z = tap split 5+4
    conv_mfma_kernel<256,9,5,2,false,false,false,true><<<dim3(256,2,2), 256, 0, stream>>>(hfb, Wk79, cb79, c79a, c79b, 256, 0);
    bn_stats_kernel<<<256, 256, 0, stream>>>(c79a, c79b, 256, 128, bn2s, bn2q);

    logits_bn_kernel<<<256, 128, 0, stream>>>(c79a, c79b, bn2s, bn2q, bn2g, bn2b, clsw, clsb, lg, 1.0f/32768.f);
    ce_kernel<<<128, 256, 0, stream>>>(lg, lab, cwts, acc2);
    crf_kernel<<<BB, 64, 0, stream>>>(lg, att, lab, cstart, ctrans, cend, numo, logzo);
    finalize_kernel<<<1, 256, 0, stream>>>(numo, logzo, acc2, (float*)d_out);
}

// Round 19
// 480.177 us; speedup vs baseline: 1.0272x; 1.0272x over previous
//
#include <hip/hip_runtime.h>
#include <hip/hip_bf16.h>
#include <math.h>

#define BB 256
#define TT 128
#define DD 1024
#define CFF 128
#define HH 128
#define G4 512
#define NK 9

typedef __attribute__((ext_vector_type(8))) short bf16x8;
typedef __attribute__((ext_vector_type(4))) float f32x4;

__device__ __forceinline__ float bf_lo(unsigned u){ union{unsigned u; float f;} v; v.u = u << 16; return v.f; }
__device__ __forceinline__ float bf_hi(unsigned u){ union{unsigned u; float f;} v; v.u = u & 0xffff0000u; return v.f; }
__device__ __forceinline__ unsigned f2bf(float x){
    union{float f; unsigned u;} v; v.f = x;
    unsigned r = v.u + 0x7fffu + ((v.u >> 16) & 1u);
    return r >> 16;
}
__device__ __forceinline__ float fsig_fast(float x){
    return __builtin_amdgcn_rcpf(1.0f + __builtin_amdgcn_exp2f(-1.44269504f * x));
}
__device__ __forceinline__ float ftanh_fast(float x){
    return 1.0f - 2.0f * __builtin_amdgcn_rcpf(1.0f + __builtin_amdgcn_exp2f(2.88539008f * x));
}
__device__ __forceinline__ float gelu_exact(float x){
    return 0.5f*x*(1.0f + erff(x*0.70710678118654752440f));
}

// ---------------- unified weight prep (single launch) ----------------
// Wxg packed by record position c = quad*16 + g*4 + e  <->  row r = g*128 + quad*4 + e
__global__ __launch_bounds__(256) void prep_all_kernel(
    const float* __restrict__ c5w, const float* __restrict__ c7w, const float* __restrict__ c9w,
    const float* __restrict__ Wihf, const float* __restrict__ Wihb,
    const float* __restrict__ bihf, const float* __restrict__ bhhf,
    const float* __restrict__ bihb, const float* __restrict__ bhhb,
    const float* __restrict__ c7b, const float* __restrict__ c9b,
    ushort* __restrict__ Wk5, ushort* __restrict__ Wk79, ushort* __restrict__ Wxg,
    float* __restrict__ bias_xg, float* __restrict__ cb79)
{
    int i = blockIdx.x*256 + threadIdx.x;
    if (i < 655360) {
        int k = i % 5, d = (i / 5) & 1023, f = i / 5120;
        Wk5[((size_t)(k*128 + f))*1024 + d] = (ushort)f2bf(c5w[((size_t)f*1024 + d)*5 + k]);
    } else if (i < 950272) {
        int j = i - 655360;
        int k = j % 9, d = (j / 9) & 255, f = j / 2304;
        int ks = k - 1;
        float v = (ks >= 0 && ks < 7) ? c7w[((size_t)f*256 + d)*7 + ks] : 0.f;
        Wk79[((size_t)(k*128 + f))*256 + d] = (ushort)f2bf(v);
    } else if (i < 1245184) {
        int j = i - 950272;
        int k = j % 9, d = (j / 9) & 255, f = j / 2304;
        Wk79[294912 + ((size_t)(k*128 + f))*256 + d] = (ushort)f2bf(c9w[((size_t)f*256 + d)*9 + k]);
    } else if (i < 1310720) {
        int j = i - 1245184;              // [0, 65536)
        int c = j >> 7, k = j & 127;
        int g = (c >> 2) & 3;
        int f = ((c >> 4) << 2) | (c & 3);
        int r = (g << 7) + f;
        Wxg[j] = (ushort)f2bf(Wihf[r*128 + k]);
    } else if (i < 1376256) {
        int j = i - 1310720;
        int c = j >> 7, k = j & 127;
        int g = (c >> 2) & 3;
        int f = ((c >> 4) << 2) | (c & 3);
        int r = (g << 7) + f;
        Wxg[65536 + j] = (ushort)f2bf(Wihb[r*128 + k]);
    } else if (i < 1376768) {
        int c = i - 1376256;
        int g = (c >> 2) & 3;
        int f = ((c >> 4) << 2) | (c & 3);
        int r = (g << 7) + f;
        bias_xg[c] = bihf[r] + bhhf[r];
    } else if (i < 1377280) {
        int c = i - 1376768;
        int g = (c >> 2) & 3;
        int f = ((c >> 4) << 2) | (c & 3);
        int r = (g << 7) + f;
        bias_xg[512 + c] = bihb[r] + bhhb[r];
    } else if (i < 1377536) {
        int j = i - 1377280;
        cb79[j] = (j < 128) ? c7b[j] : c9b[j - 128];
    }
}

// ---------------- implicit-GEMM conv via MFMA v5 (conv5 / merged conv79) ----------------
template<int CIN, int KS, int KSE_MAX, int SPLIT, bool IN_F32, bool OUT_BF16, bool CO_BY = false>
__global__ __launch_bounds__(256, 1) void conv_mfma_kernel(
    const void* __restrict__ in_v,
    const ushort* __restrict__ Wk_g,
    const float* __restrict__ bias_g,
    void* __restrict__ outA_v, void* __restrict__ outB_v,
    int OS, int co)
{
    constexpr int PAD = KS / 2;
    constexpr int ROWS = 128 + 2 * PAD;
    constexpr int NSTEP = (SPLIT == 1) ? (CIN / 64) : (CIN / 32);
    constexpr int ATOT = IN_F32 ? ROWS * 8 : ROWS * 4;
    constexpr int BTOT = KSE_MAX * 128 * 4;
    constexpr int AIT = (ATOT + 255) / 256;
    constexpr int BIT = (BTOT + 255) / 256;

    __shared__ ushort A_lds[ROWS * 32];
    __shared__ ushort B_lds[KSE_MAX * 128 * 32];

    const int tid = threadIdx.x;
    const int b   = blockIdx.x;
    const int by  = blockIdx.y;
    const int z   = blockIdx.z;
    const int dbase = (SPLIT == 1) ? z * (CIN / 2) : 0;
    const int k0    = (SPLIT == 2) ? z * KSE_MAX : 0;
    const int kse   = (SPLIT == 2) ? ((z == 0) ? KSE_MAX : (KS - KSE_MAX)) : KS;
    const ushort* __restrict__ Wk = Wk_g + (size_t)by * (size_t)(128 * CIN * KS);
    const float* __restrict__ bias = bias_g + by * 128;
    const int co_eff = co + (CO_BY ? (by << 7) : 0);

    float4 aRf[AIT];
    int4   aRb[AIT];
    int4   bR[BIT];

    auto stage_load = [&](int s) {
        const int d0 = dbase + s * 32;
        if constexpr (IN_F32) {
            const float* __restrict__ inp = (const float*)in_v;
#pragma unroll
            for (int it = 0; it < AIT; ++it) {
                int i = tid + it * 256;
                float4 v = make_float4(0.f, 0.f, 0.f, 0.f);
                if (i < ATOT) {
                    int r = i >> 3, c = i & 7;
                    int t = r - PAD;
                    if (t >= 0 && t < TT)
                        v = *reinterpret_cast<const float4*>(&inp[((size_t)b * TT + t) * CIN + d0 + c * 4]);
                }
                aRf[it] = v;
            }
        } else {
            const ushort* __restrict__ inp = (const ushort*)in_v;
#pragma unroll
            for (int it = 0; it < AIT; ++it) {
                int i = tid + it * 256;
                int4 v = make_int4(0, 0, 0, 0);
                if (i < ATOT) {
                    int r = i >> 2, c = i & 3;
                    int t = r - PAD;
                    if (t >= 0 && t < TT)
                        v = *reinterpret_cast<const int4*>(&inp[((size_t)b * TT + t) * CIN + d0 + c * 8]);
                }
                aRb[it] = v;
            }
        }
#pragma unroll
        for (int it = 0; it < BIT; ++it) {
            int i = tid + it * 256;
            int kk = i >> 9;
            int rem = i & 511;
            int f = rem >> 2, c = rem & 3;
            int4 v = make_int4(0, 0, 0, 0);
            if (kk < kse)
                v = *reinterpret_cast<const int4*>(&Wk[((size_t)((k0 + kk) * 128 + f)) * CIN + d0 + c * 8]);
            bR[it] = v;
        }
    };

    auto stage_write = [&]() {
        if constexpr (IN_F32) {
#pragma unroll
            for (int it = 0; it < AIT; ++it) {
                int i = tid + it * 256;
                if (i < ATOT) {
                    int r = i >> 3, c = i & 7;
                    float4 v = aRf[it];
                    ushort4 h;
                    h.x = (ushort)f2bf(v.x); h.y = (ushort)f2bf(v.y);
                    h.z = (ushort)f2bf(v.z); h.w = (ushort)f2bf(v.w);
                    int slot = (c >> 1) ^ (r & 3);
                    *reinterpret_cast<ushort4*>(&A_lds[r * 32 + slot * 8 + (c & 1) * 4]) = h;
                }
            }
        } else {
#pragma unroll
            for (int it = 0; it < AIT; ++it) {
                int i = tid + it * 256;
                if (i < ATOT) {
                    int r = i >> 2, c = i & 3;
                    int slot = c ^ (r & 3);
                    *reinterpret_cast<int4*>(&A_lds[r * 32 + slot * 8]) = aRb[it];
                }
            }
        }
#pragma unroll
        for (int it = 0; it < BIT; ++it) {
            int i = tid + it * 256;
            int kk = i >> 9;
            int rem = i & 511;
            int f = rem >> 2, c = rem & 3;
            int slot = c ^ (f & 3);
            *reinterpret_cast<int4*>(&B_lds[(kk * 128 + f) * 32 + slot * 8]) = bR[it];
        }
    };

    const int lane = tid & 63;
    const int wave = tid >> 6;
    const int lr = lane & 15;
    const int lk = lane >> 4;
    const int wm = wave >> 1;
    const int wn = wave & 1;

    f32x4 acc[4][4];
#pragma unroll
    for (int m = 0; m < 4; ++m)
#pragma unroll
        for (int n = 0; n < 4; ++n)
            acc[m][n] = (f32x4){0.f, 0.f, 0.f, 0.f};

    stage_load(0);
    stage_write();
    asm volatile("s_waitcnt lgkmcnt(0)" ::: "memory");
    __builtin_amdgcn_s_barrier();
    __builtin_amdgcn_sched_barrier(0);

    for (int s = 0; s < NSTEP; ++s) {
        if (s + 1 < NSTEP) stage_load(s + 1);
#pragma unroll
        for (int kk = 0; kk < KSE_MAX; ++kk) {
            bf16x8 af[4], bfr[4];
#pragma unroll
            for (int m = 0; m < 4; ++m) {
                int R = wm * 64 + m * 16 + lr + k0 + kk;
                if (kk >= kse) R = 0;
                af[m] = *reinterpret_cast<const bf16x8*>(&A_lds[R * 32 + ((lk ^ (R & 3)) * 8)]);
            }
#pragma unroll
            for (int n = 0; n < 4; ++n) {
                int Rb = kk * 128 + wn * 64 + n * 16 + lr;
                bfr[n] = *reinterpret_cast<const bf16x8*>(&B_lds[Rb * 32 + ((lk ^ (lr & 3)) * 8)]);
            }
#pragma unroll
            for (int m = 0; m < 4; ++m)
#pragma unroll
                for (int n = 0; n < 4; ++n)
                    acc[m][n] = __builtin_amdgcn_mfma_f32_16x16x32_bf16(af[m], bfr[n], acc[m][n], 0, 0, 0);
        }
        if (s + 1 < NSTEP) {
            asm volatile("s_waitcnt lgkmcnt(0)" ::: "memory");
            __builtin_amdgcn_s_barrier();
            __builtin_amdgcn_sched_barrier(0);
            stage_write();
            asm volatile("s_waitcnt lgkmcnt(0)" ::: "memory");
            __builtin_amdgcn_s_barrier();
            __builtin_amdgcn_sched_barrier(0);
        }
    }

    const bool addb = (SPLIT == 0) || (z == 0);
    void* out_v = (SPLIT != 0 && z == 1) ? outB_v : outA_v;
    float bv[4];
#pragma unroll
    for (int n = 0; n < 4; ++n) bv[n] = addb ? bias[wn * 64 + n * 16 + lr] : 0.f;
#pragma unroll
    for (int m = 0; m < 4; ++m) {
#pragma unroll
        for (int n = 0; n < 4; ++n) {
            int f = wn * 64 + n * 16 + lr;
#pragma unroll
            for (int q = 0; q < 4; ++q) {
                int trow = wm * 64 + m * 16 + lk * 4 + q;
                float val = acc[m][n][q] + bv[n];
                size_t idx = ((size_t)b * TT + trow) * (size_t)OS + co_eff + f;
                if constexpr (OUT_BF16)
                    ((ushort*)out_v)[idx] = (ushort)f2bf(val);
                else
                    ((float*)out_v)[idx] = val;
            }
        }
    }
}

// ---------------- xg GEMM: all 4 gates per block, N-axis = packed record position ----------------
// grid (256 b, 2 dir, 2 z); 512 thr / 8 waves; tile 128t x 256c; z splits c at record boundary.
// Writes xg[dir][t][b][c] with lanes spanning consecutive c -> 32B-coalesced stores;
// layout [b][quad][g][e] = exactly the LSTM's 32B per-thread records.
__global__ __launch_bounds__(512, 1) void xg_gemm_kernel(
    const ushort* __restrict__ y1h,     // (B*T,128) bf16
    const ushort* __restrict__ Wxgp,    // [dir][512 c][128 k] bf16 (packed)
    const float* __restrict__ bias_p,   // [dir][512 c]
    ushort* __restrict__ xg)            // [dir][t][b][512]
{
    __shared__ ushort A_lds[128 * 32];
    __shared__ ushort B_lds[256 * 32];

    const int tid  = threadIdx.x;
    const int b    = blockIdx.x;
    const int dir  = blockIdx.y;
    const int cbase = blockIdx.z << 8;
    const ushort* __restrict__ Wp = Wxgp + (size_t)dir * 65536 + (size_t)cbase * 128;
    const float* __restrict__ bp = bias_p + dir * 512 + cbase;

    int4 aR;
    int4 bR[2];

    auto stage_load = [&](int s) {
        const int d0 = s * 32;
        {
            int r = tid >> 2, c4 = tid & 3;
            aR = *reinterpret_cast<const int4*>(&y1h[((size_t)b * 128 + r) * 128 + d0 + c4 * 8]);
        }
#pragma unroll
        for (int it = 0; it < 2; ++it) {
            int i = tid + it * 512;
            int row = i >> 2, c4 = i & 3;
            bR[it] = *reinterpret_cast<const int4*>(&Wp[(size_t)row * 128 + d0 + c4 * 8]);
        }
    };
    auto stage_write = [&]() {
        {
            int r = tid >> 2, c4 = tid & 3;
            int slot = c4 ^ (r & 3);
            *reinterpret_cast<int4*>(&A_lds[r * 32 + slot * 8]) = aR;
        }
#pragma unroll
        for (int it = 0; it < 2; ++it) {
            int i = tid + it * 512;
            int row = i >> 2, c4 = i & 3;
            int slot = c4 ^ (row & 3);
            *reinterpret_cast<int4*>(&B_lds[row * 32 + slot * 8]) = bR[it];
        }
    };

    const int lane = tid & 63;
    const int wave = tid >> 6;     // 0..7
    const int lr = lane & 15;
    const int lk = lane >> 4;
    const int wm = wave >> 1;      // 0..3: 32-row t-stripe
    const int wn = wave & 1;       // 0..1: 128-col half

    f32x4 acc[2][8];
#pragma unroll
    for (int m = 0; m < 2; ++m)
#pragma unroll
        for (int n = 0; n < 8; ++n)
            acc[m][n] = (f32x4){0.f, 0.f, 0.f, 0.f};

    stage_load(0);
    stage_write();
    asm volatile("s_waitcnt lgkmcnt(0)" ::: "memory");
    __builtin_amdgcn_s_barrier();
    __builtin_amdgcn_sched_barrier(0);

    for (int s = 0; s < 4; ++s) {
        if (s + 1 < 4) stage_load(s + 1);
        bf16x8 af[2];
#pragma unroll
        for (int m = 0; m < 2; ++m) {
            int R = wm * 32 + m * 16 + lr;
            af[m] = *reinterpret_cast<const bf16x8*>(&A_lds[R * 32 + ((lk ^ (R & 3)) * 8)]);
        }
#pragma unroll
        for (int n = 0; n < 8; ++n) {
            int Rb = wn * 128 + n * 16 + lr;
            bf16x8 bfr = *reinterpret_cast<const bf16x8*>(&B_lds[Rb * 32 + ((lk ^ (Rb & 3)) * 8)]);
#pragma unroll
            for (int m = 0; m < 2; ++m)
                acc[m][n] = __builtin_amdgcn_mfma_f32_16x16x32_bf16(af[m], bfr, acc[m][n], 0, 0, 0);
        }
        if (s + 1 < 4) {
            asm volatile("s_waitcnt lgkmcnt(0)" ::: "memory");
            __builtin_amdgcn_s_barrier();
            __builtin_amdgcn_sched_barrier(0);
            stage_write();
            asm volatile("s_waitcnt lgkmcnt(0)" ::: "memory");
            __builtin_amdgcn_s_barrier();
            __builtin_amdgcn_sched_barrier(0);
        }
    }

    ushort* __restrict__ outp = xg + (size_t)dir * 16777216u + (size_t)b * 512u;
#pragma unroll
    for (int n = 0; n < 8; ++n) {
        int c = wn * 128 + n * 16 + lr;
        float bb = bp[c];
#pragma unroll
        for (int m = 0; m < 2; ++m) {
#pragma unroll
            for (int q = 0; q < 4; ++q) {
                int t = wm * 32 + m * 16 + lk * 4 + q;
                outp[(size_t)t * 131072u + (size_t)(cbase + c)] = (ushort)f2bf(acc[m][n][q] + bb);
            }
        }
    }
}

// ---------------- BN stats (sums partials y + y2) ----------------
__global__ __launch_bounds__(256) void bn_stats_kernel(
    const float* __restrict__ y, const float* __restrict__ y2, int C, int rows_per_blk,
    float* __restrict__ sum, float* __restrict__ sqsum)
{
    int tpc = 256 / C;
    int c = threadIdx.x & (C - 1);
    int sub = threadIdx.x / C;
    size_t r0 = (size_t)blockIdx.x * rows_per_blk;
    float s = 0.f, s2 = 0.f;
    for (int r = sub; r < rows_per_blk; r += tpc) {
        size_t i = (r0 + r)*C + c;
        float v = y[i] + y2[i];
        s += v; s2 += v*v;
    }
    __shared__ float ls[256], ls2[256];
    ls[threadIdx.x] = s; ls2[threadIdx.x] = s2;
    __syncthreads();
    if (sub == 0) {
        for (int k = 1; k < tpc; ++k) { s += ls[c + k*C]; s2 += ls2[c + k*C]; }
        atomicAdd(&sum[c], s);
        atomicAdd(&sqsum[c], s2);
    }
}

// ---------------- BN1 + GELU, bf16 output ----------------
__global__ __launch_bounds__(256) void bn_gelu_bf16_kernel(
    const float* __restrict__ y, const float* __restrict__ y2,
    const float* __restrict__ sum, const float* __restrict__ sqsum,
    const float* __restrict__ g, const float* __restrict__ beta,
    ushort* __restrict__ out, float inv_n)
{
    size_t i = (size_t)blockIdx.x*256 + threadIdx.x;
    int c = (int)(i & 127);
    float m = sum[c] * inv_n;
    float var = fmaxf(sqsum[c]*inv_n - m*m, 0.f);
    float xv = (y[i] + y2[i] - m) * rsqrtf(var + 1e-5f) * g[c] + beta[c];
    out[i] = (ushort)f2bf(gelu_exact(xv));
}

// ---------------- MFMA bi-LSTM v5b: contiguous 32B xg records (2 x dwordx4) ----------------
__global__ __launch_bounds__(512, 1) void lstm_mfma_kernel(
    const ushort* __restrict__ xg2,
    const float* __restrict__ Whhf, const float* __restrict__ Whhb,
    ushort* __restrict__ hfb)
{
    const int tid = threadIdx.x;
    const int lane = tid & 63;
    const int w = tid >> 6;
    const int jc = lane & 15;
    const int kq = lane >> 4;
    const int dir = blockIdx.x >> 4;
    const int b0 = (blockIdx.x & 15) << 4;
    const float* __restrict__ Whh = dir ? Whhb : Whhf;

    bf16x8 Wf[4][4];
#pragma unroll
    for (int g = 0; g < 4; ++g) {
        const float* wr = &Whh[(size_t)((g << 7) + (w << 4) + jc) * HH + (kq << 3)];
#pragma unroll
        for (int s = 0; s < 4; ++s) {
            float4 v0 = *reinterpret_cast<const float4*>(wr + (s << 5));
            float4 v1 = *reinterpret_cast<const float4*>(wr + (s << 5) + 4);
            union { bf16x8 v; ushort u[8]; } pk;
            pk.u[0] = (ushort)f2bf(v0.x); pk.u[1] = (ushort)f2bf(v0.y);
            pk.u[2] = (ushort)f2bf(v0.z); pk.u[3] = (ushort)f2bf(v0.w);
            pk.u[4] = (ushort)f2bf(v1.x); pk.u[5] = (ushort)f2bf(v1.y);
            pk.u[6] = (ushort)f2bf(v1.z); pk.u[7] = (ushort)f2bf(v1.w);
            Wf[g][s] = pk.v;
        }
    }

    __shared__ ushort h_lds[2][16 * 136];
    for (int i = tid; i < 16 * 136; i += 512) h_lds[0][i] = 0;
    f32x4 creg = (f32x4){0.f, 0.f, 0.f, 0.f};

    const ushort* __restrict__ xb = xg2 + (size_t)dir * 16777216u
        + (size_t)(b0 + jc) * 512u + (size_t)((w * 4 + kq) << 4);

    uint4 xA0, xA1, xB0, xB1;
    {
        int tt0 = dir ? (TT - 1) : 0;
        int tt1 = dir ? (TT - 2) : 1;
        const uint4* pA = reinterpret_cast<const uint4*>(xb + (size_t)tt0 * 131072u);
        const uint4* pB = reinterpret_cast<const uint4*>(xb + (size_t)tt1 * 131072u);
        xA0 = pA[0]; xA1 = pA[1];
        xB0 = pB[0]; xB1 = pB[1];
    }

    __syncthreads();

    int cur = 0;
    const int hrd = jc * 136 + (kq << 3);
    const int col0 = (w << 4) + (kq << 2);

    auto step = [&](int t, uint4& x0, uint4& x1) {
        const int tt_c = dir ? (TT - 1 - t) : t;
        f32x4 acc[4];
        {
            unsigned xu[8] = {x0.x, x0.y, x0.z, x0.w, x1.x, x1.y, x1.z, x1.w};
#pragma unroll
            for (int g = 0; g < 4; ++g) {
                acc[g][0] = bf_lo(xu[2*g]);
                acc[g][1] = bf_hi(xu[2*g]);
                acc[g][2] = bf_lo(xu[2*g + 1]);
                acc[g][3] = bf_hi(xu[2*g + 1]);
            }
        }
        {
            int t2 = t + 2; if (t2 >= TT) t2 = TT - 1;
            int ttn = dir ? (TT - 1 - t2) : t2;
            const uint4* p = reinterpret_cast<const uint4*>(xb + (size_t)ttn * 131072u);
            x0 = p[0]; x1 = p[1];
        }
        bf16x8 Hf[4];
#pragma unroll
        for (int s = 0; s < 4; ++s)
            Hf[s] = *reinterpret_cast<const bf16x8*>(&h_lds[cur][hrd + (s << 5)]);
#pragma unroll
        for (int s = 0; s < 4; ++s)
#pragma unroll
            for (int g = 0; g < 4; ++g)
                acc[g] = __builtin_amdgcn_mfma_f32_16x16x32_bf16(Wf[g][s], Hf[s], acc[g], 0, 0, 0);
        float hv[4];
#pragma unroll
        for (int r = 0; r < 4; ++r) {
            float iv = fsig_fast(acc[0][r]);
            float fv = fsig_fast(acc[1][r]);
            float gv = ftanh_fast(acc[2][r]);
            float ov = fsig_fast(acc[3][r]);
            float c = fv * creg[r] + iv * gv;
            creg[r] = c;
            hv[r] = ov * ftanh_fast(c);
        }
        ushort4 hb;
        hb.x = (ushort)f2bf(hv[0]); hb.y = (ushort)f2bf(hv[1]);
        hb.z = (ushort)f2bf(hv[2]); hb.w = (ushort)f2bf(hv[3]);
        const int nxt = cur ^ 1;
        *reinterpret_cast<ushort4*>(&h_lds[nxt][jc * 136 + col0]) = hb;
        *reinterpret_cast<ushort4*>(&hfb[((size_t)(b0 + jc) * TT + tt_c) * 256 + (dir << 7) + col0]) = hb;
        asm volatile("s_waitcnt lgkmcnt(0)" ::: "memory");
        __builtin_amdgcn_s_barrier();
        __builtin_amdgcn_sched_barrier(0);
        cur = nxt;
    };

    for (int t = 0; t < TT; t += 2) {
        step(t, xA0, xA1);
        step(t + 1, xB0, xB1);
    }
}

// ---------------- fused BN2 + GELU + logits (256 blocks x 128 thr) ----------------
__global__ __launch_bounds__(128) void logits_bn_kernel(
    const float* __restrict__ a, const float* __restrict__ bpart,
    const float* __restrict__ sum, const float* __restrict__ sqsum,
    const float* __restrict__ g, const float* __restrict__ beta,
    const float* __restrict__ cw, const float* __restrict__ cb,
    float* __restrict__ lg, float inv_n)
{
    __shared__ float wls[NK*256];
    __shared__ float sc_lds[256], sh_lds[256];
    for (int i = threadIdx.x; i < NK*256; i += 128) wls[i] = cw[i];
    for (int c = threadIdx.x; c < 256; c += 128) {
        float m = sum[c] * inv_n;
        float var = fmaxf(sqsum[c]*inv_n - m*m, 0.f);
        float rs = rsqrtf(var + 1e-5f);
        float s = rs * g[c];
        sc_lds[c] = s;
        sh_lds[c] = beta[c] - m * s;
    }
    __syncthreads();
    size_t row = (size_t)blockIdx.x*128 + threadIdx.x;
    const float* ar = &a[row*256];
    const float* br = &bpart[row*256];
    float acc[NK];
#pragma unroll
    for (int k = 0; k < NK; ++k) acc[k] = 0.f;
    for (int c = 0; c < 256; c += 4) {
        float4 av = *reinterpret_cast<const float4*>(&ar[c]);
        float4 bv = *reinterpret_cast<const float4*>(&br[c]);
        float vv[4] = {av.x + bv.x, av.y + bv.y, av.z + bv.z, av.w + bv.w};
#pragma unroll
        for (int j = 0; j < 4; ++j) {
            float xv = vv[j] * sc_lds[c + j] + sh_lds[c + j];
            float f = gelu_exact(xv);
#pragma unroll
            for (int k = 0; k < NK; ++k)
                acc[k] += f * wls[k*256 + c + j];
        }
    }
#pragma unroll
    for (int k = 0; k < NK; ++k) lg[row*NK + k] = acc[k] + cb[k];
}

// ---------------- weighted CE ----------------
__global__ __launch_bounds__(256) void ce_kernel(
    const float* __restrict__ lg, const int* __restrict__ labels,
    const float* __restrict__ cw, float* __restrict__ acc2)
{
    size_t i = (size_t)blockIdx.x*256 + threadIdx.x;
    const float* l = &lg[i*NK];
    float mx = -1e30f;
#pragma unroll
    for (int k = 0; k < NK; ++k) mx = fmaxf(mx, l[k]);
    float se = 0.f;
#pragma unroll
    for (int k = 0; k < NK; ++k) se += expf(l[k] - mx);
    float lz = mx + logf(se);
    int y = labels[i];
    bool valid = (y != -100);
    int yi = valid ? y : 0;
    float nll = lz - l[yi];
    float wv = valid ? cw[yi] : 0.f;
    __shared__ float s1[256], s2[256];
    s1[threadIdx.x] = wv*nll;
    s2[threadIdx.x] = wv;
    __syncthreads();
    for (int s = 128; s > 0; s >>= 1) {
        if (threadIdx.x < s) { s1[threadIdx.x] += s1[threadIdx.x + s]; s2[threadIdx.x] += s2[threadIdx.x + s]; }
        __syncthreads();
    }
    if (threadIdx.x == 0) { atomicAdd(&acc2[0], s1[0]); atomicAdd(&acc2[1], s2[0]); }
}

// ---------------- CRF ----------------
__global__ __launch_bounds__(64) void crf_kernel(
    const float* __restrict__ lg, const int* __restrict__ att,
    const int* __restrict__ labels, const float* __restrict__ startv,
    const float* __restrict__ trans, const float* __restrict__ endv,
    float* __restrict__ numo, float* __restrict__ logzo)
{
    int b = blockIdx.x;
    int lane = threadIdx.x;
    int lane_c = (lane < NK) ? lane : 0;
    const float* em = &lg[(size_t)b*TT*NK];
    float tr[NK];
#pragma unroll
    for (int i = 0; i < NK; ++i) tr[i] = trans[i*NK + lane_c];
    float score = startv[lane_c] + em[lane_c];

    for (int t = 1; t < TT; ++t) {
        int lt = labels[b*TT + t];
        bool m = (att[b*TT + t] != 0) && (lt != -100);
        float vals[NK];
#pragma unroll
        for (int i = 0; i < NK; ++i)
            vals[i] = __shfl(score, i, 64) + tr[i];
        if (m) {
            float mx = vals[0];
#pragma unroll
            for (int i = 1; i < NK; ++i) mx = fmaxf(mx, vals[i]);
            float sm = 0.f;
#pragma unroll
            for (int i = 0; i < NK; ++i) sm += expf(vals[i] - mx);
            score = mx + logf(sm) + em[t*NK + lane_c];
        }
    }
    float fin = (lane < NK) ? (score + endv[lane_c]) : -1e30f;
    float mx = -1e30f;
#pragma unroll
    for (int i = 0; i < NK; ++i) mx = fmaxf(mx, __shfl(fin, i, 64));
    float sm = 0.f;
#pragma unroll
    for (int i = 0; i < NK; ++i) sm += expf(__shfl(fin, i, 64) - mx);
    if (lane == 0) logzo[b] = mx + logf(sm);

    if (lane == 0) {
        int l0 = labels[b*TT];
        int tag0 = (l0 == -100) ? 0 : l0;
        bool m0 = (att[b*TT] != 0) && (l0 != -100);
        float num = startv[tag0] + em[tag0];
        int prev = tag0;
        int cnt = m0 ? 1 : 0;
        for (int t = 1; t < TT; ++t) {
            int lt = labels[b*TT + t];
            bool m = (att[b*TT + t] != 0) && (lt != -100);
            int tag = (lt == -100) ? 0 : lt;
            if (m) { num += trans[prev*NK + tag] + em[t*NK + tag]; cnt++; }
            prev = tag;
        }
        int le = cnt - 1; if (le < 0) le = 0; if (le >= TT) le = TT - 1;
        int ll = labels[b*TT + le];
        int ltag = (ll == -100) ? 0 : ll;
        num += endv[ltag];
        numo[b] = num;
    }
}

__global__ __launch_bounds__(256) void finalize_kernel(
    const float* __restrict__ numo, const float* __restrict__ logzo,
    const float* __restrict__ acc2, float* __restrict__ out)
{
    __shared__ float red[256];
    int tid = threadIdx.x;
    red[tid] = numo[tid] - logzo[tid];
    __syncthreads();
    for (int s = 128; s > 0; s >>= 1) {
        if (tid < s) red[tid] += red[tid + s];
        __syncthreads();
    }
    if (tid == 0) {
        float crf = -(red[0] / (float)BB);
        float ce = acc2[0] / acc2[1];
        out[0] = 0.8f*crf + 0.2f*ce;
    }
}

extern "C" void kernel_launch(void* const* d_in, const int* in_sizes, int n_in,
                              void* d_out, int out_size, void* d_ws, size_t ws_size,
                              hipStream_t stream)
{
    const float* emb   = (const float*)d_in[0];
    const int*   att   = (const int*)  d_in[1];
    const int*   lab   = (const int*)  d_in[2];
    const float* c5w   = (const float*)d_in[3];
    const float* c5b   = (const float*)d_in[4];
    const float* bn1g  = (const float*)d_in[5];
    const float* bn1b  = (const float*)d_in[6];
    const float* Wihf  = (const float*)d_in[7];
    const float* Whhf  = (const float*)d_in[8];
    const float* bihf  = (const float*)d_in[9];
    const float* bhhf  = (const float*)d_in[10];
    const float* Wihb  = (const float*)d_in[11];
    const float* Whhb  = (const float*)d_in[12];
    const float* bihb  = (const float*)d_in[13];
    const float* bhhb  = (const float*)d_in[14];
    const float* c7w   = (const float*)d_in[15];
    const float* c7b   = (const float*)d_in[16];
    const float* c9w   = (const float*)d_in[17];
    const float* c9b   = (const float*)d_in[18];
    const float* bn2g  = (const float*)d_in[19];
    const float* bn2b  = (const float*)d_in[20];
    const float* clsw  = (const float*)d_in[21];
    const float* clsb  = (const float*)d_in[22];
    const float* cstart= (const float*)d_in[23];
    const float* ctrans= (const float*)d_in[24];
    const float* cend  = (const float*)d_in[25];
    const float* cwts  = (const float*)d_in[26];
    (void)in_sizes; (void)n_in; (void)out_size; (void)ws_size;

    char* wsb = (char*)d_ws;
    size_t off = 0;
    auto alloc = [&](size_t bytes) { void* p = wsb + off; off += (bytes + 255) & ~(size_t)255; return p; };
    float*  y1      = (float*) alloc((size_t)4194304*4);   // (B*T,128) f32
    ushort* xg      = (ushort*)alloc((size_t)2*16777216*2);// [dir][t][b][quad][g][e] bf16 (64MB)
    ushort* hfb     = (ushort*)alloc((size_t)8388608*2);   // (B*T,256) bf16
    ushort* y1h     = (ushort*)alloc((size_t)4194304*2);   // (B*T,128) bf16 (post-BN1-GELU)
    float*  lg      = (float*) alloc((size_t)294912*4);
    ushort* Wk5     = (ushort*)alloc((size_t)655360*2);
    ushort* Wk79    = (ushort*)alloc((size_t)589824*2);    // [conv7 padded to 9 taps | conv9]
    ushort* Wxg     = (ushort*)alloc((size_t)131072*2);    // packed by record position
    float*  bias_xg = (float*) alloc((size_t)1024*4);
    float*  cb79    = (float*) alloc((size_t)256*4);
    float*  stats   = (float*) alloc((size_t)2048*4);
    // aliases into the (temporally dead) xg region:
    float* y1b  = (float*)xg;                        // conv5 z=1 partial (16MB), dead before xg conv
    float* c79a = (float*)xg;                        // conv7/9 z=0 partials (32MB), after lstm
    float* c79b = (float*)(xg + 16777216);           // conv7/9 z=1 partials (32MB)
    float* bn1s = stats;
    float* bn1q = stats + 128;
    float* bn2s = stats + 256;
    float* bn2q = stats + 512;
    float* acc2 = stats + 768;
    float* numo = stats + 770;
    float* logzo = numo + 256;

    hipMemsetAsync(stats, 0, 770*sizeof(float), stream);

    prep_all_kernel<<<5381, 256, 0, stream>>>(c5w, c7w, c9w, Wihf, Wihb,
        bihf, bhhf, bihb, bhhb, c7b, c9b, Wk5, Wk79, Wxg, bias_xg, cb79);

    // conv5: K-channel split (z=0: d<512, z=1: d>=512) -> y1 / y1b
    conv_mfma_kernel<1024,5,5,1,true,false><<<dim3(256,1,2), 256, 0, stream>>>(emb, Wk5, c5b, y1, y1b, 128, 0);
    bn_stats_kernel<<<256, 256, 0, stream>>>(y1, y1b, 128, 128, bn1s, bn1q);
    bn_gelu_bf16_kernel<<<16384, 256, 0, stream>>>(y1, y1b, bn1s, bn1q, bn1g, bn1b, y1h, 1.0f/32768.f);

    xg_gemm_kernel<<<dim3(256,2,2), 512, 0, stream>>>(y1h, Wxg, bias_xg, xg);
    lstm_mfma_kernel<<<32, 512, 0, stream>>>(xg, Whhf, Whhb, hfb);

    // merged conv7+conv9 (conv7 tap-padded to 9): by = weight set + col offset, z = tap split 5+4
    conv_mfma_kernel<256,9,5,2,false,false,true><<<dim3(256,2,2), 256, 0, stream>>>(hfb, Wk79, cb79, c79a, c79b, 256, 0);
    bn_stats_kernel<<<256, 256, 0, stream>>>(c79a, c79b, 256, 128, bn2s, bn2q);

    logits_bn_kernel<<<256, 128, 0, stream>>>(c79a, c79b, bn2s, bn2q, bn2g, bn2b, clsw, clsb, lg, 1.0f/32768.f);
    ce_kernel<<<128, 256, 0, stream>>>(lg, lab, cwts, acc2);
    crf_kernel<<<BB, 64, 0, stream>>>(lg, att, lab, cstart, ctrans, cend, numo, logzo);
    finalize_kernel<<<1, 256, 0, stream>>>(numo, logzo, acc2, (float*)d_out);
}

// Round 20
// 478.636 us; speedup vs baseline: 1.0305x; 1.0032x over previous
//
#include <hip/hip_runtime.h>
#include <hip/hip_bf16.h>
#include <math.h>

#define BB 256
#define TT 128
#define DD 1024
#define CFF 128
#define HH 128
#define G4 512
#define NK 9

typedef __attribute__((ext_vector_type(8))) short bf16x8;
typedef __attribute__((ext_vector_type(4))) float f32x4;

__device__ __forceinline__ float bf_lo(unsigned u){ union{unsigned u; float f;} v; v.u = u << 16; return v.f; }
__device__ __forceinline__ float bf_hi(unsigned u){ union{unsigned u; float f;} v; v.u = u & 0xffff0000u; return v.f; }
__device__ __forceinline__ float bfu2f(ushort u){ union{unsigned u; float f;} v; v.u = ((unsigned)u) << 16; return v.f; }
__device__ __forceinline__ unsigned f2bf(float x){
    union{float f; unsigned u;} v; v.f = x;
    unsigned r = v.u + 0x7fffu + ((v.u >> 16) & 1u);
    return r >> 16;
}
__device__ __forceinline__ float fsig_fast(float x){
    return __builtin_amdgcn_rcpf(1.0f + __builtin_amdgcn_exp2f(-1.44269504f * x));
}
__device__ __forceinline__ float ftanh_fast(float x){
    return 1.0f - 2.0f * __builtin_amdgcn_rcpf(1.0f + __builtin_amdgcn_exp2f(2.88539008f * x));
}
__device__ __forceinline__ float gelu_exact(float x){
    return 0.5f*x*(1.0f + erff(x*0.70710678118654752440f));
}

// ---------------- unified weight prep (single launch) ----------------
// Wxg packed by record position c = quad*16 + g*4 + e  <->  row r = g*128 + quad*4 + e
__global__ __launch_bounds__(256) void prep_all_kernel(
    const float* __restrict__ c5w, const float* __restrict__ c7w, const float* __restrict__ c9w,
    const float* __restrict__ Wihf, const float* __restrict__ Wihb,
    const float* __restrict__ bihf, const float* __restrict__ bhhf,
    const float* __restrict__ bihb, const float* __restrict__ bhhb,
    const float* __restrict__ c7b, const float* __restrict__ c9b,
    ushort* __restrict__ Wk5, ushort* __restrict__ Wk79, ushort* __restrict__ Wxg,
    float* __restrict__ bias_xg, float* __restrict__ cb79)
{
    int i = blockIdx.x*256 + threadIdx.x;
    if (i < 655360) {
        int k = i % 5, d = (i / 5) & 1023, f = i / 5120;
        Wk5[((size_t)(k*128 + f))*1024 + d] = (ushort)f2bf(c5w[((size_t)f*1024 + d)*5 + k]);
    } else if (i < 950272) {
        int j = i - 655360;
        int k = j % 9, d = (j / 9) & 255, f = j / 2304;
        int ks = k - 1;
        float v = (ks >= 0 && ks < 7) ? c7w[((size_t)f*256 + d)*7 + ks] : 0.f;
        Wk79[((size_t)(k*128 + f))*256 + d] = (ushort)f2bf(v);
    } else if (i < 1245184) {
        int j = i - 950272;
        int k = j % 9, d = (j / 9) & 255, f = j / 2304;
        Wk79[294912 + ((size_t)(k*128 + f))*256 + d] = (ushort)f2bf(c9w[((size_t)f*256 + d)*9 + k]);
    } else if (i < 1310720) {
        int j = i - 1245184;              // [0, 65536)
        int c = j >> 7, k = j & 127;
        int g = (c >> 2) & 3;
        int f = ((c >> 4) << 2) | (c & 3);
        int r = (g << 7) + f;
        Wxg[j] = (ushort)f2bf(Wihf[r*128 + k]);
    } else if (i < 1376256) {
        int j = i - 1310720;
        int c = j >> 7, k = j & 127;
        int g = (c >> 2) & 3;
        int f = ((c >> 4) << 2) | (c & 3);
        int r = (g << 7) + f;
        Wxg[65536 + j] = (ushort)f2bf(Wihb[r*128 + k]);
    } else if (i < 1376768) {
        int c = i - 1376256;
        int g = (c >> 2) & 3;
        int f = ((c >> 4) << 2) | (c & 3);
        int r = (g << 7) + f;
        bias_xg[c] = bihf[r] + bhhf[r];
    } else if (i < 1377280) {
        int c = i - 1376768;
        int g = (c >> 2) & 3;
        int f = ((c >> 4) << 2) | (c & 3);
        int r = (g << 7) + f;
        bias_xg[512 + c] = bihb[r] + bhhb[r];
    } else if (i < 1377536) {
        int j = i - 1377280;
        cb79[j] = (j < 128) ? c7b[j] : c9b[j - 128];
    }
}

// ---------------- implicit-GEMM conv via MFMA v5 (conv5 / merged conv79) ----------------
template<int CIN, int KS, int KSE_MAX, int SPLIT, bool IN_F32, bool OUT_BF16, bool CO_BY = false>
__global__ __launch_bounds__(256, 1) void conv_mfma_kernel(
    const void* __restrict__ in_v,
    const ushort* __restrict__ Wk_g,
    const float* __restrict__ bias_g,
    void* __restrict__ outA_v, void* __restrict__ outB_v,
    int OS, int co)
{
    constexpr int PAD = KS / 2;
    constexpr int ROWS = 128 + 2 * PAD;
    constexpr int NSTEP = (SPLIT == 1) ? (CIN / 64) : (CIN / 32);
    constexpr int ATOT = IN_F32 ? ROWS * 8 : ROWS * 4;
    constexpr int BTOT = KSE_MAX * 128 * 4;
    constexpr int AIT = (ATOT + 255) / 256;
    constexpr int BIT = (BTOT + 255) / 256;

    __shared__ ushort A_lds[ROWS * 32];
    __shared__ ushort B_lds[KSE_MAX * 128 * 32];

    const int tid = threadIdx.x;
    const int b   = blockIdx.x;
    const int by  = blockIdx.y;
    const int z   = blockIdx.z;
    const int dbase = (SPLIT == 1) ? z * (CIN / 2) : 0;
    const int k0    = (SPLIT == 2) ? z * KSE_MAX : 0;
    const int kse   = (SPLIT == 2) ? ((z == 0) ? KSE_MAX : (KS - KSE_MAX)) : KS;
    const ushort* __restrict__ Wk = Wk_g + (size_t)by * (size_t)(128 * CIN * KS);
    const float* __restrict__ bias = bias_g + by * 128;
    const int co_eff = co + (CO_BY ? (by << 7) : 0);

    float4 aRf[AIT];
    int4   aRb[AIT];
    int4   bR[BIT];

    auto stage_load = [&](int s) {
        const int d0 = dbase + s * 32;
        if constexpr (IN_F32) {
            const float* __restrict__ inp = (const float*)in_v;
#pragma unroll
            for (int it = 0; it < AIT; ++it) {
                int i = tid + it * 256;
                float4 v = make_float4(0.f, 0.f, 0.f, 0.f);
                if (i < ATOT) {
                    int r = i >> 3, c = i & 7;
                    int t = r - PAD;
                    if (t >= 0 && t < TT)
                        v = *reinterpret_cast<const float4*>(&inp[((size_t)b * TT + t) * CIN + d0 + c * 4]);
                }
                aRf[it] = v;
            }
        } else {
            const ushort* __restrict__ inp = (const ushort*)in_v;
#pragma unroll
            for (int it = 0; it < AIT; ++it) {
                int i = tid + it * 256;
                int4 v = make_int4(0, 0, 0, 0);
                if (i < ATOT) {
                    int r = i >> 2, c = i & 3;
                    int t = r - PAD;
                    if (t >= 0 && t < TT)
                        v = *reinterpret_cast<const int4*>(&inp[((size_t)b * TT + t) * CIN + d0 + c * 8]);
                }
                aRb[it] = v;
            }
        }
#pragma unroll
        for (int it = 0; it < BIT; ++it) {
            int i = tid + it * 256;
            int kk = i >> 9;
            int rem = i & 511;
            int f = rem >> 2, c = rem & 3;
            int4 v = make_int4(0, 0, 0, 0);
            if (kk < kse)
                v = *reinterpret_cast<const int4*>(&Wk[((size_t)((k0 + kk) * 128 + f)) * CIN + d0 + c * 8]);
            bR[it] = v;
        }
    };

    auto stage_write = [&]() {
        if constexpr (IN_F32) {
#pragma unroll
            for (int it = 0; it < AIT; ++it) {
                int i = tid + it * 256;
                if (i < ATOT) {
                    int r = i >> 3, c = i & 7;
                    float4 v = aRf[it];
                    ushort4 h;
                    h.x = (ushort)f2bf(v.x); h.y = (ushort)f2bf(v.y);
                    h.z = (ushort)f2bf(v.z); h.w = (ushort)f2bf(v.w);
                    int slot = (c >> 1) ^ (r & 3);
                    *reinterpret_cast<ushort4*>(&A_lds[r * 32 + slot * 8 + (c & 1) * 4]) = h;
                }
            }
        } else {
#pragma unroll
            for (int it = 0; it < AIT; ++it) {
                int i = tid + it * 256;
                if (i < ATOT) {
                    int r = i >> 2, c = i & 3;
                    int slot = c ^ (r & 3);
                    *reinterpret_cast<int4*>(&A_lds[r * 32 + slot * 8]) = aRb[it];
                }
            }
        }
#pragma unroll
        for (int it = 0; it < BIT; ++it) {
            int i = tid + it * 256;
            int kk = i >> 9;
            int rem = i & 511;
            int f = rem >> 2, c = rem & 3;
            int slot = c ^ (f & 3);
            *reinterpret_cast<int4*>(&B_lds[(kk * 128 + f) * 32 + slot * 8]) = bR[it];
        }
    };

    const int lane = tid & 63;
    const int wave = tid >> 6;
    const int lr = lane & 15;
    const int lk = lane >> 4;
    const int wm = wave >> 1;
    const int wn = wave & 1;

    f32x4 acc[4][4];
#pragma unroll
    for (int m = 0; m < 4; ++m)
#pragma unroll
        for (int n = 0; n < 4; ++n)
            acc[m][n] = (f32x4){0.f, 0.f, 0.f, 0.f};

    stage_load(0);
    stage_write();
    asm volatile("s_waitcnt lgkmcnt(0)" ::: "memory");
    __builtin_amdgcn_s_barrier();
    __builtin_amdgcn_sched_barrier(0);

    for (int s = 0; s < NSTEP; ++s) {
        if (s + 1 < NSTEP) stage_load(s + 1);
#pragma unroll
        for (int kk = 0; kk < KSE_MAX; ++kk) {
            bf16x8 af[4], bfr[4];
#pragma unroll
            for (int m = 0; m < 4; ++m) {
                int R = wm * 64 + m * 16 + lr + k0 + kk;
                if (kk >= kse) R = 0;
                af[m] = *reinterpret_cast<const bf16x8*>(&A_lds[R * 32 + ((lk ^ (R & 3)) * 8)]);
            }
#pragma unroll
            for (int n = 0; n < 4; ++n) {
                int Rb = kk * 128 + wn * 64 + n * 16 + lr;
                bfr[n] = *reinterpret_cast<const bf16x8*>(&B_lds[Rb * 32 + ((lk ^ (lr & 3)) * 8)]);
            }
#pragma unroll
            for (int m = 0; m < 4; ++m)
#pragma unroll
                for (int n = 0; n < 4; ++n)
                    acc[m][n] = __builtin_amdgcn_mfma_f32_16x16x32_bf16(af[m], bfr[n], acc[m][n], 0, 0, 0);
        }
        if (s + 1 < NSTEP) {
            asm volatile("s_waitcnt lgkmcnt(0)" ::: "memory");
            __builtin_amdgcn_s_barrier();
            __builtin_amdgcn_sched_barrier(0);
            stage_write();
            asm volatile("s_waitcnt lgkmcnt(0)" ::: "memory");
            __builtin_amdgcn_s_barrier();
            __builtin_amdgcn_sched_barrier(0);
        }
    }

    const bool addb = (SPLIT == 0) || (z == 0);
    void* out_v = (SPLIT != 0 && z == 1) ? outB_v : outA_v;
    float bv[4];
#pragma unroll
    for (int n = 0; n < 4; ++n) bv[n] = addb ? bias[wn * 64 + n * 16 + lr] : 0.f;
#pragma unroll
    for (int m = 0; m < 4; ++m) {
#pragma unroll
        for (int n = 0; n < 4; ++n) {
            int f = wn * 64 + n * 16 + lr;
#pragma unroll
            for (int q = 0; q < 4; ++q) {
                int trow = wm * 64 + m * 16 + lk * 4 + q;
                float val = acc[m][n][q] + bv[n];
                size_t idx = ((size_t)b * TT + trow) * (size_t)OS + co_eff + f;
                if constexpr (OUT_BF16)
                    ((ushort*)out_v)[idx] = (ushort)f2bf(val);
                else
                    ((float*)out_v)[idx] = val;
            }
        }
    }
}

// ---------------- xg GEMM: all 4 gates per block, N-axis = packed record position ----------------
__global__ __launch_bounds__(512, 1) void xg_gemm_kernel(
    const ushort* __restrict__ y1h,     // (B*T,128) bf16
    const ushort* __restrict__ Wxgp,    // [dir][512 c][128 k] bf16 (packed)
    const float* __restrict__ bias_p,   // [dir][512 c]
    ushort* __restrict__ xg)            // [dir][t][b][512]
{
    __shared__ ushort A_lds[128 * 32];
    __shared__ ushort B_lds[256 * 32];

    const int tid  = threadIdx.x;
    const int b    = blockIdx.x;
    const int dir  = blockIdx.y;
    const int cbase = blockIdx.z << 8;
    const ushort* __restrict__ Wp = Wxgp + (size_t)dir * 65536 + (size_t)cbase * 128;
    const float* __restrict__ bp = bias_p + dir * 512 + cbase;

    int4 aR;
    int4 bR[2];

    auto stage_load = [&](int s) {
        const int d0 = s * 32;
        {
            int r = tid >> 2, c4 = tid & 3;
            aR = *reinterpret_cast<const int4*>(&y1h[((size_t)b * 128 + r) * 128 + d0 + c4 * 8]);
        }
#pragma unroll
        for (int it = 0; it < 2; ++it) {
            int i = tid + it * 512;
            int row = i >> 2, c4 = i & 3;
            bR[it] = *reinterpret_cast<const int4*>(&Wp[(size_t)row * 128 + d0 + c4 * 8]);
        }
    };
    auto stage_write = [&]() {
        {
            int r = tid >> 2, c4 = tid & 3;
            int slot = c4 ^ (r & 3);
            *reinterpret_cast<int4*>(&A_lds[r * 32 + slot * 8]) = aR;
        }
#pragma unroll
        for (int it = 0; it < 2; ++it) {
            int i = tid + it * 512;
            int row = i >> 2, c4 = i & 3;
            int slot = c4 ^ (row & 3);
            *reinterpret_cast<int4*>(&B_lds[row * 32 + slot * 8]) = bR[it];
        }
    };

    const int lane = tid & 63;
    const int wave = tid >> 6;     // 0..7
    const int lr = lane & 15;
    const int lk = lane >> 4;
    const int wm = wave >> 1;      // 0..3: 32-row t-stripe
    const int wn = wave & 1;       // 0..1: 128-col half

    f32x4 acc[2][8];
#pragma unroll
    for (int m = 0; m < 2; ++m)
#pragma unroll
        for (int n = 0; n < 8; ++n)
            acc[m][n] = (f32x4){0.f, 0.f, 0.f, 0.f};

    stage_load(0);
    stage_write();
    asm volatile("s_waitcnt lgkmcnt(0)" ::: "memory");
    __builtin_amdgcn_s_barrier();
    __builtin_amdgcn_sched_barrier(0);

    for (int s = 0; s < 4; ++s) {
        if (s + 1 < 4) stage_load(s + 1);
        bf16x8 af[2];
#pragma unroll
        for (int m = 0; m < 2; ++m) {
            int R = wm * 32 + m * 16 + lr;
            af[m] = *reinterpret_cast<const bf16x8*>(&A_lds[R * 32 + ((lk ^ (R & 3)) * 8)]);
        }
#pragma unroll
        for (int n = 0; n < 8; ++n) {
            int Rb = wn * 128 + n * 16 + lr;
            bf16x8 bfr = *reinterpret_cast<const bf16x8*>(&B_lds[Rb * 32 + ((lk ^ (Rb & 3)) * 8)]);
#pragma unroll
            for (int m = 0; m < 2; ++m)
                acc[m][n] = __builtin_amdgcn_mfma_f32_16x16x32_bf16(af[m], bfr, acc[m][n], 0, 0, 0);
        }
        if (s + 1 < 4) {
            asm volatile("s_waitcnt lgkmcnt(0)" ::: "memory");
            __builtin_amdgcn_s_barrier();
            __builtin_amdgcn_sched_barrier(0);
            stage_write();
            asm volatile("s_waitcnt lgkmcnt(0)" ::: "memory");
            __builtin_amdgcn_s_barrier();
            __builtin_amdgcn_sched_barrier(0);
        }
    }

    ushort* __restrict__ outp = xg + (size_t)dir * 16777216u + (size_t)b * 512u;
#pragma unroll
    for (int n = 0; n < 8; ++n) {
        int c = wn * 128 + n * 16 + lr;
        float bb = bp[c];
#pragma unroll
        for (int m = 0; m < 2; ++m) {
#pragma unroll
            for (int q = 0; q < 4; ++q) {
                int t = wm * 32 + m * 16 + lk * 4 + q;
                outp[(size_t)t * 131072u + (size_t)(cbase + c)] = (ushort)f2bf(acc[m][n][q] + bb);
            }
        }
    }
}

// ---------------- BN stats (sums bf16 partials y + y2) ----------------
__global__ __launch_bounds__(256) void bn_stats_kernel(
    const ushort* __restrict__ y, const ushort* __restrict__ y2, int C, int rows_per_blk,
    float* __restrict__ sum, float* __restrict__ sqsum)
{
    int tpc = 256 / C;
    int c = threadIdx.x & (C - 1);
    int sub = threadIdx.x / C;
    size_t r0 = (size_t)blockIdx.x * rows_per_blk;
    float s = 0.f, s2 = 0.f;
    for (int r = sub; r < rows_per_blk; r += tpc) {
        size_t i = (r0 + r)*C + c;
        float v = bfu2f(y[i]) + bfu2f(y2[i]);
        s += v; s2 += v*v;
    }
    __shared__ float ls[256], ls2[256];
    ls[threadIdx.x] = s; ls2[threadIdx.x] = s2;
    __syncthreads();
    if (sub == 0) {
        for (int k = 1; k < tpc; ++k) { s += ls[c + k*C]; s2 += ls2[c + k*C]; }
        atomicAdd(&sum[c], s);
        atomicAdd(&sqsum[c], s2);
    }
}

// ---------------- BN1 + GELU, bf16 in/out ----------------
__global__ __launch_bounds__(256) void bn_gelu_bf16_kernel(
    const ushort* __restrict__ y, const ushort* __restrict__ y2,
    const float* __restrict__ sum, const float* __restrict__ sqsum,
    const float* __restrict__ g, const float* __restrict__ beta,
    ushort* __restrict__ out, float inv_n)
{
    size_t i = (size_t)blockIdx.x*256 + threadIdx.x;
    int c = (int)(i & 127);
    float m = sum[c] * inv_n;
    float var = fmaxf(sqsum[c]*inv_n - m*m, 0.f);
    float xv = (bfu2f(y[i]) + bfu2f(y2[i]) - m) * rsqrtf(var + 1e-5f) * g[c] + beta[c];
    out[i] = (ushort)f2bf(gelu_exact(xv));
}

// ---------------- MFMA bi-LSTM v5b: contiguous 32B xg records (2 x dwordx4) ----------------
__global__ __launch_bounds__(512, 1) void lstm_mfma_kernel(
    const ushort* __restrict__ xg2,
    const float* __restrict__ Whhf, const float* __restrict__ Whhb,
    ushort* __restrict__ hfb)
{
    const int tid = threadIdx.x;
    const int lane = tid & 63;
    const int w = tid >> 6;
    const int jc = lane & 15;
    const int kq = lane >> 4;
    const int dir = blockIdx.x >> 4;
    const int b0 = (blockIdx.x & 15) << 4;
    const float* __restrict__ Whh = dir ? Whhb : Whhf;

    bf16x8 Wf[4][4];
#pragma unroll
    for (int g = 0; g < 4; ++g) {
        const float* wr = &Whh[(size_t)((g << 7) + (w << 4) + jc) * HH + (kq << 3)];
#pragma unroll
        for (int s = 0; s < 4; ++s) {
            float4 v0 = *reinterpret_cast<const float4*>(wr + (s << 5));
            float4 v1 = *reinterpret_cast<const float4*>(wr + (s << 5) + 4);
            union { bf16x8 v; ushort u[8]; } pk;
            pk.u[0] = (ushort)f2bf(v0.x); pk.u[1] = (ushort)f2bf(v0.y);
            pk.u[2] = (ushort)f2bf(v0.z); pk.u[3] = (ushort)f2bf(v0.w);
            pk.u[4] = (ushort)f2bf(v1.x); pk.u[5] = (ushort)f2bf(v1.y);
            pk.u[6] = (ushort)f2bf(v1.z); pk.u[7] = (ushort)f2bf(v1.w);
            Wf[g][s] = pk.v;
        }
    }

    __shared__ ushort h_lds[2][16 * 136];
    for (int i = tid; i < 16 * 136; i += 512) h_lds[0][i] = 0;
    f32x4 creg = (f32x4){0.f, 0.f, 0.f, 0.f};

    const ushort* __restrict__ xb = xg2 + (size_t)dir * 16777216u
        + (size_t)(b0 + jc) * 512u + (size_t)((w * 4 + kq) << 4);

    uint4 xA0, xA1, xB0, xB1;
    {
        int tt0 = dir ? (TT - 1) : 0;
        int tt1 = dir ? (TT - 2) : 1;
        const uint4* pA = reinterpret_cast<const uint4*>(xb + (size_t)tt0 * 131072u);
        const uint4* pB = reinterpret_cast<const uint4*>(xb + (size_t)tt1 * 131072u);
        xA0 = pA[0]; xA1 = pA[1];
        xB0 = pB[0]; xB1 = pB[1];
    }

    __syncthreads();

    int cur = 0;
    const int hrd = jc * 136 + (kq << 3);
    const int col0 = (w << 4) + (kq << 2);

    auto step = [&](int t, uint4& x0, uint4& x1) {
        const int tt_c = dir ? (TT - 1 - t) : t;
        f32x4 acc[4];
        {
            unsigned xu[8] = {x0.x, x0.y, x0.z, x0.w, x1.x, x1.y, x1.z, x1.w};
#pragma unroll
            for (int g = 0; g < 4; ++g) {
                acc[g][0] = bf_lo(xu[2*g]);
                acc[g][1] = bf_hi(xu[2*g]);
                acc[g][2] = bf_lo(xu[2*g + 1]);
                acc[g][3] = bf_hi(xu[2*g + 1]);
            }
        }
        {
            int t2 = t + 2; if (t2 >= TT) t2 = TT - 1;
            int ttn = dir ? (TT - 1 - t2) : t2;
            const uint4* p = reinterpret_cast<const uint4*>(xb + (size_t)ttn * 131072u);
            x0 = p[0]; x1 = p[1];
        }
        bf16x8 Hf[4];
#pragma unroll
        for (int s = 0; s < 4; ++s)
            Hf[s] = *reinterpret_cast<const bf16x8*>(&h_lds[cur][hrd + (s << 5)]);
#pragma unroll
        for (int s = 0; s < 4; ++s)
#pragma unroll
            for (int g = 0; g < 4; ++g)
                acc[g] = __builtin_amdgcn_mfma_f32_16x16x32_bf16(Wf[g][s], Hf[s], acc[g], 0, 0, 0);
        float hv[4];
#pragma unroll
        for (int r = 0; r < 4; ++r) {
            float iv = fsig_fast(acc[0][r]);
            float fv = fsig_fast(acc[1][r]);
            float gv = ftanh_fast(acc[2][r]);
            float ov = fsig_fast(acc[3][r]);
            float c = fv * creg[r] + iv * gv;
            creg[r] = c;
            hv[r] = ov * ftanh_fast(c);
        }
        ushort4 hb;
        hb.x = (ushort)f2bf(hv[0]); hb.y = (ushort)f2bf(hv[1]);
        hb.z = (ushort)f2bf(hv[2]); hb.w = (ushort)f2bf(hv[3]);
        const int nxt = cur ^ 1;
        *reinterpret_cast<ushort4*>(&h_lds[nxt][jc * 136 + col0]) = hb;
        *reinterpret_cast<ushort4*>(&hfb[((size_t)(b0 + jc) * TT + tt_c) * 256 + (dir << 7) + col0]) = hb;
        asm volatile("s_waitcnt lgkmcnt(0)" ::: "memory");
        __builtin_amdgcn_s_barrier();
        __builtin_amdgcn_sched_barrier(0);
        cur = nxt;
    };

    for (int t = 0; t < TT; t += 2) {
        step(t, xA0, xA1);
        step(t + 1, xB0, xB1);
    }
}

// ---------------- fused BN2 + GELU + logits (bf16 partials in) ----------------
__global__ __launch_bounds__(128) void logits_bn_kernel(
    const ushort* __restrict__ a, const ushort* __restrict__ bpart,
    const float* __restrict__ sum, const float* __restrict__ sqsum,
    const float* __restrict__ g, const float* __restrict__ beta,
    const float* __restrict__ cw, const float* __restrict__ cb,
    float* __restrict__ lg, float inv_n)
{
    __shared__ float wls[NK*256];
    __shared__ float sc_lds[256], sh_lds[256];
    for (int i = threadIdx.x; i < NK*256; i += 128) wls[i] = cw[i];
    for (int c = threadIdx.x; c < 256; c += 128) {
        float m = sum[c] * inv_n;
        float var = fmaxf(sqsum[c]*inv_n - m*m, 0.f);
        float rs = rsqrtf(var + 1e-5f);
        float s = rs * g[c];
        sc_lds[c] = s;
        sh_lds[c] = beta[c] - m * s;
    }
    __syncthreads();
    size_t row = (size_t)blockIdx.x*128 + threadIdx.x;
    const ushort* ar = &a[row*256];
    const ushort* br = &bpart[row*256];
    float acc[NK];
#pragma unroll
    for (int k = 0; k < NK; ++k) acc[k] = 0.f;
    for (int c = 0; c < 256; c += 4) {
        ushort4 av = *reinterpret_cast<const ushort4*>(&ar[c]);
        ushort4 bv = *reinterpret_cast<const ushort4*>(&br[c]);
        float vv[4] = {bfu2f(av.x) + bfu2f(bv.x), bfu2f(av.y) + bfu2f(bv.y),
                       bfu2f(av.z) + bfu2f(bv.z), bfu2f(av.w) + bfu2f(bv.w)};
#pragma unroll
        for (int j = 0; j < 4; ++j) {
            float xv = vv[j] * sc_lds[c + j] + sh_lds[c + j];
            float f = gelu_exact(xv);
#pragma unroll
            for (int k = 0; k < NK; ++k)
                acc[k] += f * wls[k*256 + c + j];
        }
    }
#pragma unroll
    for (int k = 0; k < NK; ++k) lg[row*NK + k] = acc[k] + cb[k];
}

// ---------------- weighted CE ----------------
__global__ __launch_bounds__(256) void ce_kernel(
    const float* __restrict__ lg, const int* __restrict__ labels,
    const float* __restrict__ cw, float* __restrict__ acc2)
{
    size_t i = (size_t)blockIdx.x*256 + threadIdx.x;
    const float* l = &lg[i*NK];
    float mx = -1e30f;
#pragma unroll
    for (int k = 0; k < NK; ++k) mx = fmaxf(mx, l[k]);
    float se = 0.f;
#pragma unroll
    for (int k = 0; k < NK; ++k) se += expf(l[k] - mx);
    float lz = mx + logf(se);
    int y = labels[i];
    bool valid = (y != -100);
    int yi = valid ? y : 0;
    float nll = lz - l[yi];
    float wv = valid ? cw[yi] : 0.f;
    __shared__ float s1[256], s2[256];
    s1[threadIdx.x] = wv*nll;
    s2[threadIdx.x] = wv;
    __syncthreads();
    for (int s = 128; s > 0; s >>= 1) {
        if (threadIdx.x < s) { s1[threadIdx.x] += s1[threadIdx.x + s]; s2[threadIdx.x] += s2[threadIdx.x + s]; }
        __syncthreads();
    }
    if (threadIdx.x == 0) { atomicAdd(&acc2[0], s1[0]); atomicAdd(&acc2[1], s2[0]); }
}

// ---------------- CRF ----------------
__global__ __launch_bounds__(64) void crf_kernel(
    const float* __restrict__ lg, const int* __restrict__ att,
    const int* __restrict__ labels, const float* __restrict__ startv,
    const float* __restrict__ trans, const float* __restrict__ endv,
    float* __restrict__ numo, float* __restrict__ logzo)
{
    int b = blockIdx.x;
    int lane = threadIdx.x;
    int lane_c = (lane < NK) ? lane : 0;
    const float* em = &lg[(size_t)b*TT*NK];
    float tr[NK];
#pragma unroll
    for (int i = 0; i < NK; ++i) tr[i] = trans[i*NK + lane_c];
    float score = startv[lane_c] + em[lane_c];

    for (int t = 1; t < TT; ++t) {
        int lt = labels[b*TT + t];
        bool m = (att[b*TT + t] != 0) && (lt != -100);
        float vals[NK];
#pragma unroll
        for (int i = 0; i < NK; ++i)
            vals[i] = __shfl(score, i, 64) + tr[i];
        if (m) {
            float mx = vals[0];
#pragma unroll
            for (int i = 1; i < NK; ++i) mx = fmaxf(mx, vals[i]);
            float sm = 0.f;
#pragma unroll
            for (int i = 0; i < NK; ++i) sm += expf(vals[i] - mx);
            score = mx + logf(sm) + em[t*NK + lane_c];
        }
    }
    float fin = (lane < NK) ? (score + endv[lane_c]) : -1e30f;
    float mx = -1e30f;
#pragma unroll
    for (int i = 0; i < NK; ++i) mx = fmaxf(mx, __shfl(fin, i, 64));
    float sm = 0.f;
#pragma unroll
    for (int i = 0; i < NK; ++i) sm += expf(__shfl(fin, i, 64) - mx);
    if (lane == 0) logzo[b] = mx + logf(sm);

    if (lane == 0) {
        int l0 = labels[b*TT];
        int tag0 = (l0 == -100) ? 0 : l0;
        bool m0 = (att[b*TT] != 0) && (l0 != -100);
        float num = startv[tag0] + em[tag0];
        int prev = tag0;
        int cnt = m0 ? 1 : 0;
        for (int t = 1; t < TT; ++t) {
            int lt = labels[b*TT + t];
            bool m = (att[b*TT + t] != 0) && (lt != -100);
            int tag = (lt == -100) ? 0 : lt;
            if (m) { num += trans[prev*NK + tag] + em[t*NK + tag]; cnt++; }
            prev = tag;
        }
        int le = cnt - 1; if (le < 0) le = 0; if (le >= TT) le = TT - 1;
        int ll = labels[b*TT + le];
        int ltag = (ll == -100) ? 0 : ll;
        num += endv[ltag];
        numo[b] = num;
    }
}

__global__ __launch_bounds__(256) void finalize_kernel(
    const float* __restrict__ numo, const float* __restrict__ logzo,
    const float* __restrict__ acc2, float* __restrict__ out)
{
    __shared__ float red[256];
    int tid = threadIdx.x;
    red[tid] = numo[tid] - logzo[tid];
    __syncthreads();
    for (int s = 128; s > 0; s >>= 1) {
        if (tid < s) red[tid] += red[tid + s];
        __syncthreads();
    }
    if (tid == 0) {
        float crf = -(red[0] / (float)BB);
        float ce = acc2[0] / acc2[1];
        out[0] = 0.8f*crf + 0.2f*ce;
    }
}

extern "C" void kernel_launch(void* const* d_in, const int* in_sizes, int n_in,
                              void* d_out, int out_size, void* d_ws, size_t ws_size,
                              hipStream_t stream)
{
    const float* emb   = (const float*)d_in[0];
    const int*   att   = (const int*)  d_in[1];
    const int*   lab   = (const int*)  d_in[2];
    const float* c5w   = (const float*)d_in[3];
    const float* c5b   = (const float*)d_in[4];
    const float* bn1g  = (const float*)d_in[5];
    const float* bn1b  = (const float*)d_in[6];
    const float* Wihf  = (const float*)d_in[7];
    const float* Whhf  = (const float*)d_in[8];
    const float* bihf  = (const float*)d_in[9];
    const float* bhhf  = (const float*)d_in[10];
    const float* Wihb  = (const float*)d_in[11];
    const float* Whhb  = (const float*)d_in[12];
    const float* bihb  = (const float*)d_in[13];
    const float* bhhb  = (const float*)d_in[14];
    const float* c7w   = (const float*)d_in[15];
    const float* c7b   = (const float*)d_in[16];
    const float* c9w   = (const float*)d_in[17];
    const float* c9b   = (const float*)d_in[18];
    const float* bn2g  = (const float*)d_in[19];
    const float* bn2b  = (const float*)d_in[20];
    const float* clsw  = (const float*)d_in[21];
    const float* clsb  = (const float*)d_in[22];
    const float* cstart= (const float*)d_in[23];
    const float* ctrans= (const float*)d_in[24];
    const float* cend  = (const float*)d_in[25];
    const float* cwts  = (const float*)d_in[26];
    (void)in_sizes; (void)n_in; (void)out_size; (void)ws_size;

    char* wsb = (char*)d_ws;
    size_t off = 0;
    auto alloc = [&](size_t bytes) { void* p = wsb + off; off += (bytes + 255) & ~(size_t)255; return p; };
    ushort* y1      = (ushort*)alloc((size_t)4194304*2);   // (B*T,128) bf16 conv5 z=0 partial
    ushort* xg      = (ushort*)alloc((size_t)2*16777216*2);// [dir][t][b][quad][g][e] bf16 (64MB)
    ushort* hfb     = (ushort*)alloc((size_t)8388608*2);   // (B*T,256) bf16
    ushort* y1h     = (ushort*)alloc((size_t)4194304*2);   // (B*T,128) bf16 (post-BN1-GELU)
    float*  lg      = (float*) alloc((size_t)294912*4);
    ushort* Wk5     = (ushort*)alloc((size_t)655360*2);
    ushort* Wk79    = (ushort*)alloc((size_t)589824*2);    // [conv7 padded to 9 taps | conv9]
    ushort* Wxg     = (ushort*)alloc((size_t)131072*2);    // packed by record position
    float*  bias_xg = (float*) alloc((size_t)1024*4);
    float*  cb79    = (float*) alloc((size_t)256*4);
    float*  stats   = (float*) alloc((size_t)2048*4);
    // aliases into the (temporally dead) xg region:
    ushort* y1b  = xg;                         // conv5 z=1 partial (8MB), dead before xg_gemm
    ushort* c79a = xg;                         // conv79 z=0 partials (16MB), after lstm
    ushort* c79b = xg + 16777216;              // conv79 z=1 partials (16MB)
    float* bn1s = stats;
    float* bn1q = stats + 128;
    float* bn2s = stats + 256;
    float* bn2q = stats + 512;
    float* acc2 = stats + 768;
    float* numo = stats + 770;
    float* logzo = numo + 256;

    hipMemsetAsync(stats, 0, 770*sizeof(float), stream);

    prep_all_kernel<<<5381, 256, 0, stream>>>(c5w, c7w, c9w, Wihf, Wihb,
        bihf, bhhf, bihb, bhhb, c7b, c9b, Wk5, Wk79, Wxg, bias_xg, cb79);

    // conv5: K-channel split (z=0: d<512, z=1: d>=512) -> y1 / y1b (bf16 partials)
    conv_mfma_kernel<1024,5,5,1,true,true><<<dim3(256,1,2), 256, 0, stream>>>(emb, Wk5, c5b, y1, y1b, 128, 0);
    bn_stats_kernel<<<256, 256, 0, stream>>>(y1, y1b, 128, 128, bn1s, bn1q);
    bn_gelu_bf16_kernel<<<16384, 256, 0, stream>>>(y1, y1b, bn1s, bn1q, bn1g, bn1b, y1h, 1.0f/32768.f);

    xg_gemm_kernel<<<dim3(256,2,2), 512, 0, stream>>>(y1h, Wxg, bias_xg, xg);
    lstm_mfma_kernel<<<32, 512, 0, stream>>>(xg, Whhf, Whhb, hfb);

    // merged conv7+conv9 (conv7 tap-padded to 9): by = weight set + col offset, z = tap split 5+4
    conv_mfma_kernel<256,9,5,2,false,true,true><<<dim3(256,2,2), 256, 0, stream>>>(hfb, Wk79, cb79, c79a, c79b, 256, 0);
    bn_stats_kernel<<<256, 256, 0, stream>>>(c79a, c79b, 256, 128, bn2s, bn2q);

    logits_bn_kernel<<<256, 128, 0, stream>>>(c79a, c79b, bn2s, bn2q, bn2g, bn2b, clsw, clsb, lg, 1.0f/32768.f);
    ce_kernel<<<128, 256, 0, stream>>>(lg, lab, cwts, acc2);
    crf_kernel<<<BB, 64, 0, stream>>>(lg, att, lab, cstart, ctrans, cend, numo, logzo);
    finalize_kernel<<<1, 256, 0, stream>>>(numo, logzo, acc2, (float*)d_out);
}